// Round 15
// baseline (765.952 us; speedup 1.0000x reference)
//
#include <hip/hip_runtime.h>

// EMD approx-match (Fan et al. approxmatch.cu), B=8, N=M=4096.
// Levels 0-1: box-pruned full-array sweeps (dual-radius fused C+A).
// Level 2: C-only pruned sweep (A(3) moved to compact domain).
// Levels 3-8: active-set compaction; compact buffers keep cell-sort order,
// per-group bboxes allow box-pruning of compact sweeps at l=3; l>=4 stays
// branch-free pipelined. Level 9 closed form.
// R14 FIX: compact padding carries w=0 (real position for tight bboxes,
// zero weight so unguarded register-side cost accumulations stay zero).

#define BB 8
#define NN 4096
#define MM 4096
#define NPTS 4096

constexpr int   BLK   = 256;
constexpr int   S     = 16;
constexpr int   R     = 4;
constexpr int   RPB   = (BLK / S) * R;   // 64
constexpr int   CHUNK = 2048;
constexpr int   G     = (CHUNK / S) / 4; // 32 groups of 64 cols
constexpr float TAU   = 1e-8f;

#if defined(__has_builtin)
#if __has_builtin(__builtin_amdgcn_exp2f)
#define EXP2F(x) __builtin_amdgcn_exp2f(x)
#endif
#if __has_builtin(__builtin_amdgcn_logf)
#define LOG2F(x) __builtin_amdgcn_logf(x)
#endif
#endif
#ifndef EXP2F
#define EXP2F(x) exp2f(x)
#endif
#ifndef LOG2F
#define LOG2F(x) log2f(x)
#endif

// ---------- counting sort into 64 spatial cells (both clouds, one launch) ----------
__global__ void emd_sort(const float* __restrict__ x1, const float* __restrict__ x2,
                         float* __restrict__ s1, float* __restrict__ s2) {
    __shared__ int hist[64];
    __shared__ int cur[64];
    const int blk = blockIdx.x;
    const float* src = (blk < BB) ? x1 + (size_t)blk * NPTS * 3
                                  : x2 + (size_t)(blk - BB) * NPTS * 3;
    float* dst = (blk < BB) ? s1 + (size_t)blk * NPTS * 3
                            : s2 + (size_t)(blk - BB) * NPTS * 3;
    for (int i = threadIdx.x; i < 64; i += BLK) hist[i] = 0;
    __syncthreads();
    for (int i = threadIdx.x; i < NPTS; i += BLK) {
        float x = src[3*i], y = src[3*i+1], z = src[3*i+2];
        int cx = (int)(x * 4.0f); cx = cx < 0 ? 0 : (cx > 3 ? 3 : cx);
        int cy = (int)(y * 4.0f); cy = cy < 0 ? 0 : (cy > 3 ? 3 : cy);
        int cz = (int)(z * 4.0f); cz = cz < 0 ? 0 : (cz > 3 ? 3 : cz);
        atomicAdd(&hist[(cx << 4) | (cy << 2) | cz], 1);
    }
    __syncthreads();
    if (threadIdx.x == 0) {
        int acc = 0;
        for (int k = 0; k < 64; ++k) { cur[k] = acc; acc += hist[k]; }
    }
    __syncthreads();
    for (int i = threadIdx.x; i < NPTS; i += BLK) {
        float x = src[3*i], y = src[3*i+1], z = src[3*i+2];
        int cx = (int)(x * 4.0f); cx = cx < 0 ? 0 : (cx > 3 ? 3 : cx);
        int cy = (int)(y * 4.0f); cy = cy < 0 ? 0 : (cy > 3 ? 3 : cy);
        int cz = (int)(z * 4.0f); cz = cz < 0 ? 0 : (cz > 3 ? 3 : cz);
        int idx = atomicAdd(&cur[(cx << 4) | (cy << 2) | cz], 1);
        dst[3*idx] = x; dst[3*idx+1] = y; dst[3*idx+2] = z;
    }
}

// ---------- 16- and 64-point bboxes of sorted clouds, one launch ----------
__global__ void emd_bbox_all(const float* __restrict__ x1s,
                             const float* __restrict__ x2s,
                             float* __restrict__ bb1_16, float* __restrict__ bb1_64,
                             float* __restrict__ bb2_16, float* __restrict__ bb2_64) {
    const int PER = BB * 256 + BB * 64;   // per cloud
    int id = blockIdx.x;
    int cloud = id / PER, r = id % PER;
    const float* xs = cloud ? x2s : x1s;
    float* bb; int gp, grp;
    if (r < BB * 256) { gp = 16; grp = r; bb = cloud ? bb2_16 : bb1_16; }
    else             { gp = 64; grp = r - BB * 256; bb = cloud ? bb2_64 : bb1_64; }
    const int lane = threadIdx.x;
    float xlo = 1e30f, xhi = -1e30f, ylo = 1e30f, yhi = -1e30f,
          zlo = 1e30f, zhi = -1e30f;
    if (lane < gp) {
        const float* p = xs + ((size_t)grp * gp + lane) * 3;
        xlo = xhi = p[0]; ylo = yhi = p[1]; zlo = zhi = p[2];
    }
    #pragma unroll
    for (int d = 1; d < 64; d <<= 1) {
        xlo = fminf(xlo, __shfl_xor(xlo, d)); xhi = fmaxf(xhi, __shfl_xor(xhi, d));
        ylo = fminf(ylo, __shfl_xor(ylo, d)); yhi = fmaxf(yhi, __shfl_xor(yhi, d));
        zlo = fminf(zlo, __shfl_xor(zlo, d)); zhi = fmaxf(zhi, __shfl_xor(zhi, d));
    }
    if (lane == 0) {
        float* o = bb + (size_t)grp * 6;
        o[0]=xlo; o[1]=xhi; o[2]=ylo; o[3]=yhi; o[4]=zlo; o[5]=zhi;
    }
}

__global__ void emd_init(float* __restrict__ satl, float* __restrict__ satr,
                         float* __restrict__ bsum, float* __restrict__ slsum,
                         float* __restrict__ scal, float* __restrict__ out) {
    int i = blockIdx.x * blockDim.x + threadIdx.x;
    if (i < BB * NN) satl[i] = 1.0f;
    if (i < BB * MM) satr[i] = 1.0f;
    if (i < BB)      bsum[i] = 0.0f;
    if (i < BB)      slsum[i] = 0.0f;
    if (i < BB * 5)  scal[i] = 0.0f;
    if (i == 0)      out[0]  = 0.0f;
}

// ---------- merged active-set compaction + compact-group bboxes ----------
__global__ void compact_all(const float* __restrict__ xyz1s,
                            const float* __restrict__ xyz2s,
                            const float* __restrict__ satl,
                            const float* __restrict__ satr,
                            float* __restrict__ sl,
                            float4* __restrict__ rowBuf, int* __restrict__ rIdx,
                            int* __restrict__ rCnt,
                            float4* __restrict__ colBuf, int* __restrict__ cIdx,
                            int* __restrict__ cCnt,
                            float* __restrict__ rb16c, float* __restrict__ rb64c,
                            float* __restrict__ cb16c, float* __restrict__ cb64c) {
    __shared__ int cnts[BLK];
    const bool isRow = blockIdx.x >= BB;
    const int b = isRow ? (blockIdx.x - BB) : blockIdx.x;
    const int PER = NPTS / BLK;   // 16
    const float* sb = (isRow ? satl : satr) + (size_t)b * NPTS;
    const float* xb = (isRow ? xyz1s : xyz2s) + (size_t)b * NPTS * 3;
    float* slb = sl + (size_t)b * NN;
    float4* buf = isRow ? (rowBuf + (size_t)b * NN) : (colBuf + (size_t)b * MM);
    int*    idx = isRow ? (rIdx + (size_t)b * NN)   : (cIdx + (size_t)b * MM);
    const int st = threadIdx.x * PER;
    int c = 0;
    for (int i = 0; i < PER; ++i) c += (sb[st + i] > TAU) ? 1 : 0;
    cnts[threadIdx.x] = c;
    __syncthreads();
    for (int d = 1; d < BLK; d <<= 1) {
        int v = cnts[threadIdx.x];
        int u = (threadIdx.x >= d) ? cnts[threadIdx.x - d] : 0;
        __syncthreads();
        cnts[threadIdx.x] = v + u;
        __syncthreads();
    }
    const int total = cnts[BLK - 1];
    int off = cnts[threadIdx.x] - c;
    if (isRow) {
        for (int i = 0; i < PER; ++i) {
            int n = st + i;
            if (sb[n] > TAU) {
                buf[off] = make_float4(xb[3*n], xb[3*n+1], xb[3*n+2], slb[n]);
                idx[off] = n;
                ++off;
            } else if (slb[n] != 0.0f) {
                slb[n] = 0.0f;
            }
        }
    } else {
        for (int i = 0; i < PER; ++i) {
            int m = st + i;
            if (sb[m] > TAU) {
                buf[off] = make_float4(xb[3*m], xb[3*m+1], xb[3*m+2], sb[m]);
                idx[off] = m;
                ++off;
            }
        }
    }
    for (int i = total + threadIdx.x; i < NPTS; i += BLK) idx[i] = 0;
    __syncthreads();
    float4 lastv = make_float4(0.f, 0.f, 0.f, 0.f);
    if (total > 0) lastv = buf[total - 1];
    // FIX: pad with the last point's POSITION (tight boxes) but ZERO weight,
    // so unguarded register-side reads contribute nothing to cost/sums.
    for (int i = total + threadIdx.x; i < NPTS; i += BLK)
        buf[i] = make_float4(lastv.x, lastv.y, lastv.z, 0.0f);
    if (threadIdx.x == 0) { if (isRow) rCnt[b] = total; else cCnt[b] = total; }
    __syncthreads();
    // compact-group bboxes: 256 x 16-point, then 64 x 64-point (union of 4)
    float* b16 = (isRow ? rb16c : cb16c) + (size_t)b * 256 * 6;
    float* b64 = (isRow ? rb64c : cb64c) + (size_t)b * 64 * 6;
    {
        int g16 = threadIdx.x;   // 0..255
        float xlo = 1e30f, xhi = -1e30f, ylo = 1e30f, yhi = -1e30f,
              zlo = 1e30f, zhi = -1e30f;
        for (int i = 0; i < 16; ++i) {
            float4 v = buf[g16 * 16 + i];
            xlo = fminf(xlo, v.x); xhi = fmaxf(xhi, v.x);
            ylo = fminf(ylo, v.y); yhi = fmaxf(yhi, v.y);
            zlo = fminf(zlo, v.z); zhi = fmaxf(zhi, v.z);
        }
        float* o = b16 + (size_t)g16 * 6;
        o[0]=xlo; o[1]=xhi; o[2]=ylo; o[3]=yhi; o[4]=zlo; o[5]=zhi;
    }
    __syncthreads();
    if (threadIdx.x < 64) {
        float xlo = 1e30f, xhi = -1e30f, ylo = 1e30f, yhi = -1e30f,
              zlo = 1e30f, zhi = -1e30f;
        for (int k = 0; k < 4; ++k) {
            float* i16 = b16 + (size_t)(threadIdx.x * 4 + k) * 6;
            xlo = fminf(xlo, i16[0]); xhi = fmaxf(xhi, i16[1]);
            ylo = fminf(ylo, i16[2]); yhi = fmaxf(yhi, i16[3]);
            zlo = fminf(zlo, i16[4]); zhi = fmaxf(zhi, i16[5]);
        }
        float* o = b64 + (size_t)threadIdx.x * 6;
        o[0]=xlo; o[1]=xhi; o[2]=ylo; o[3]=yhi; o[4]=zlo; o[5]=zhi;
    }
}

// ---------- shared macros ----------
#define AB_LOAD(vv, gg)                                          \
    _Pragma("unroll")                                            \
    for (int k = 0; k < 4; ++k) vv[k] = q[((gg)*4 + k)*S + s];

#define AB_COMP(vv)                                              \
    _Pragma("unroll")                                            \
    for (int k = 0; k < 4; ++k) {                                \
        float4 v = vv[k];                                        \
        _Pragma("unroll")                                        \
        for (int r = 0; r < R; ++r) {                            \
            float a0 = v.w + cpp[r];                             \
            float a1 = fmaf(zs[r], v.z, a0);                     \
            float a2 = fmaf(ys[r], v.y, a1);                     \
            float arg = fmaf(xs[r], v.x, a2);                    \
            acc[r] += EXP2F(arg);                                \
        }                                                        \
    }

#define RED_S(v)                                                 \
    v += __shfl_xor(v, 1);  v += __shfl_xor(v, 2);               \
    v += __shfl_xor(v, 4);  v += __shfl_xor(v, 8);

#define RED_W(v)                                                 \
    v += __shfl_xor(v, 1);  v += __shfl_xor(v, 2);               \
    v += __shfl_xor(v, 4);  v += __shfl_xor(v, 8);               \
    v += __shfl_xor(v, 16); v += __shfl_xor(v, 32);

#define BOX_SETUP(rbb)                                           \
    const float* rb = (rbb) + (size_t)(b * 256 + tile * 4 + (threadIdx.x >> 6)) * 6; \
    const float rx0 = rb[0], rx1 = rb[1], ry0 = rb[2], ry1 = rb[3], \
                rz0 = rb[4], rz1 = rb[5];

#define BOX_D2M(cbb, c0, gs, d2m)                                \
    const float* cb = (cbb) + (size_t)(b * 64 + ((c0) >> 6) + (gs)) * 6; \
    float gx = fmaxf(0.0f, fmaxf(cb[0] - rx1, rx0 - cb[1]));     \
    float gy = fmaxf(0.0f, fmaxf(cb[2] - ry1, ry0 - cb[3]));     \
    float gz = fmaxf(0.0f, fmaxf(cb[4] - rz1, rz0 - cb[5]));     \
    float d2m = fmaf(gx, gx, fmaf(gy, gy, gz * gz));

// ---------- Pass A (level 0, pruned) ----------
__global__ __launch_bounds__(BLK, 2) void emd_passA_p(
        const float* __restrict__ xyz1, const float* __restrict__ xyz2,
        const float* __restrict__ satl, const float* __restrict__ satr,
        float* __restrict__ sl, const float* __restrict__ rbb,
        const float* __restrict__ cbb, float c, float T) {
    __shared__ float4 q[CHUNK];
    const int b    = blockIdx.x / (NN / RPB);
    const int tile = blockIdx.x % (NN / RPB);
    const float* x2b = xyz2 + (size_t)b * MM * 3;
    const float* srb = satr + (size_t)b * MM;

    const int g = threadIdx.x / S, s = threadIdx.x % S;
    const int n0 = tile * RPB + g * R;
    const float* p = xyz1 + ((size_t)b * NN + n0) * 3;
    const float m2c = -2.0f * c;
    float xs[R], ys[R], zs[R], cpp[R], acc[R];
    #pragma unroll
    for (int r = 0; r < R; ++r) {
        float x = p[3*r], y = p[3*r+1], z = p[3*r+2];
        cpp[r] = c * (x*x + y*y + z*z);
        xs[r] = m2c * x; ys[r] = m2c * y; zs[r] = m2c * z;
        acc[r] = 0.0f;
    }
    BOX_SETUP(rbb);

    for (int c0 = 0; c0 < MM; c0 += CHUNK) {
        __syncthreads();
        for (int m = threadIdx.x; m < CHUNK; m += BLK) {
            int mm = c0 + m;
            float xx = x2b[3*mm], yy = x2b[3*mm+1], zz = x2b[3*mm+2];
            float qq = xx*xx + yy*yy + zz*zz;
            q[m] = make_float4(xx, yy, zz, fmaf(c, qq, LOG2F(srb[mm])));
        }
        __syncthreads();
        for (int gs = 0; gs < G; ++gs) {
            BOX_D2M(cbb, c0, gs, d2m);
            if (d2m > T) continue;
            float4 va[4];
            AB_LOAD(va, gs);
            AB_COMP(va);
        }
    }
    #pragma unroll
    for (int r = 0; r < R; ++r) { RED_S(acc[r]); }
    if (s == 0) {
        #pragma unroll
        for (int r = 0; r < R; ++r) {
            int gi = b * NN + n0 + r;
            sl[gi] = satl[gi] / (acc[r] + 1e-9f);
        }
    }
}

// ---------- Pass B (levels 0..2, pruned, full arrays) ----------
__global__ __launch_bounds__(BLK, 2) void emd_passB_p(
        const float* __restrict__ xyz1, const float* __restrict__ xyz2,
        const float* __restrict__ sl, float* __restrict__ satr,
        float* __restrict__ sr2, const float* __restrict__ rbb,
        const float* __restrict__ cbb, float c, float T) {
    __shared__ float4 q[CHUNK];
    const int b    = blockIdx.x / (MM / RPB);
    const int tile = blockIdx.x % (MM / RPB);
    const float* x1b = xyz1 + (size_t)b * NN * 3;
    const float* slb = sl + (size_t)b * NN;

    const int g = threadIdx.x / S, s = threadIdx.x % S;
    const int m0 = tile * RPB + g * R;
    const float* qp = xyz2 + ((size_t)b * MM + m0) * 3;
    const float m2c = -2.0f * c;
    float xs[R], ys[R], zs[R], cpp[R], acc[R];
    #pragma unroll
    for (int r = 0; r < R; ++r) {
        float x = qp[3*r], y = qp[3*r+1], z = qp[3*r+2];
        cpp[r] = c * (x*x + y*y + z*z);
        xs[r] = m2c * x; ys[r] = m2c * y; zs[r] = m2c * z;
        acc[r] = 0.0f;
    }
    BOX_SETUP(rbb);

    for (int c0 = 0; c0 < NN; c0 += CHUNK) {
        __syncthreads();
        for (int n = threadIdx.x; n < CHUNK; n += BLK) {
            int nn = c0 + n;
            float xx = x1b[3*nn], yy = x1b[3*nn+1], zz = x1b[3*nn+2];
            float pp = xx*xx + yy*yy + zz*zz;
            q[n] = make_float4(xx, yy, zz, fmaf(c, pp, LOG2F(slb[nn])));
        }
        __syncthreads();
        for (int gs = 0; gs < G; ++gs) {
            BOX_D2M(cbb, c0, gs, d2m);
            if (d2m > T) continue;
            float4 va[4];
            AB_LOAD(va, gs);
            AB_COMP(va);
        }
    }
    #pragma unroll
    for (int r = 0; r < R; ++r) { RED_S(acc[r]); }
    if (s == 0) {
        #pragma unroll
        for (int r = 0; r < R; ++r) {
            int gi = b * MM + m0 + r;
            float sr    = satr[gi];
            float ss2   = acc[r] * sr;
            float ratio = fminf(sr / (ss2 + 1e-9f), 1.0f);
            float sn    = fmaxf(sr - ss2 * ratio, 0.0f);
            sr2[gi]  = sr * ratio;
            satr[gi] = sn;
        }
    }
}

// ---------- Fused C(l)+A(l+1), dual-radius pruned (levels 0..1) ----------
#define CA0_LOAD(vv, ww, gg)                                     \
    _Pragma("unroll")                                            \
    for (int k = 0; k < 4; ++k) {                                \
        int idx = ((gg)*4 + k)*S + s;                            \
        vv[k] = q[idx]; ww[k] = w[idx];                          \
    }

#define CA0_COMP(vv, ww)                                         \
    _Pragma("unroll")                                            \
    for (int k = 0; k < 4; ++k) {                                \
        float4 v = vv[k]; float2 wv = ww[k];                     \
        _Pragma("unroll")                                        \
        for (int r = 0; r < R; ++r) {                            \
            float a0 = v.w + cnpp[r];                            \
            float a1 = fmaf(zs[r], v.z, a0);                     \
            float a2 = fmaf(ys[r], v.y, a1);                     \
            float arg = fmaf(xs[r], v.x, a2);                    \
            float en  = EXP2F(arg);                              \
            acc2[r] = fmaf(en, wv.y, acc2[r]);                   \
            float e2 = en * en;                                  \
            float t  = (e2 * e2) * wv.x;                         \
            rd[r]   += t;                                        \
            costA[r] = fmaf(t, arg, costA[r]);                   \
        }                                                        \
    }

#define CA0_COMP_AONLY(vv, ww)                                   \
    _Pragma("unroll")                                            \
    for (int k = 0; k < 4; ++k) {                                \
        float4 v = vv[k]; float2 wv = ww[k];                     \
        _Pragma("unroll")                                        \
        for (int r = 0; r < R; ++r) {                            \
            float a0 = v.w + cnpp[r];                            \
            float a1 = fmaf(zs[r], v.z, a0);                     \
            float a2 = fmaf(ys[r], v.y, a1);                     \
            float arg = fmaf(xs[r], v.x, a2);                    \
            float en  = EXP2F(arg);                              \
            acc2[r] = fmaf(en, wv.y, acc2[r]);                   \
        }                                                        \
    }

__global__ __launch_bounds__(BLK, 2) void emd_passCA0_p(
        const float* __restrict__ xyz1, const float* __restrict__ xyz2,
        float* __restrict__ sl, float* __restrict__ satl,
        const float* __restrict__ sr2, const float* __restrict__ satr_next,
        float* __restrict__ out, const float* __restrict__ rbb,
        const float* __restrict__ cbb, float cl, float cn,
        float T, float TC) {
    __shared__ float4 q[CHUNK];
    __shared__ float2 w[CHUNK];
    const int b    = blockIdx.x / (NN / RPB);
    const int tile = blockIdx.x % (NN / RPB);
    const float* x2b = xyz2 + (size_t)b * MM * 3;
    const float* s2b = sr2 + (size_t)b * MM;
    const float* srb = satr_next + (size_t)b * MM;

    const int g = threadIdx.x / S, s = threadIdx.x % S;
    const int n0 = tile * RPB + g * R;
    const float* pp_ = xyz1 + ((size_t)b * NN + n0) * 3;
    const float m2cn = -2.0f * cn;
    const float icn  = 1.0f / cn;
    float xs[R], ys[R], zs[R], cnpp[R], rd[R], costA[R], acc2[R], slv[R];
    #pragma unroll
    for (int r = 0; r < R; ++r) {
        float x = pp_[3*r], y = pp_[3*r+1], z = pp_[3*r+2];
        cnpp[r] = cn * (x*x + y*y + z*z);
        xs[r] = m2cn * x; ys[r] = m2cn * y; zs[r] = m2cn * z;
        rd[r] = 0.0f; costA[r] = 0.0f; acc2[r] = 0.0f;
        slv[r] = sl[b * NN + n0 + r];
    }
    BOX_SETUP(rbb);

    for (int c0 = 0; c0 < MM; c0 += CHUNK) {
        __syncthreads();
        for (int m = threadIdx.x; m < CHUNK; m += BLK) {
            int mm = c0 + m;
            float xx = x2b[3*mm], yy = x2b[3*mm+1], zz = x2b[3*mm+2];
            float qq = xx*xx + yy*yy + zz*zz;
            q[m] = make_float4(xx, yy, zz, cn * qq);
            w[m] = make_float2(s2b[mm], srb[mm]);
        }
        __syncthreads();
        for (int gs = 0; gs < G; ++gs) {
            BOX_D2M(cbb, c0, gs, d2m);
            if (d2m > T) continue;
            float4 va[4]; float2 wa[4];
            CA0_LOAD(va, wa, gs);
            if (d2m > TC) {
                CA0_COMP_AONLY(va, wa);
            } else {
                CA0_COMP(va, wa);
            }
        }
    }

    #pragma unroll
    for (int r = 0; r < R; ++r) { RED_S(rd[r]); RED_S(acc2[r]); }

    float csum = 0.0f;
    #pragma unroll
    for (int r = 0; r < R; ++r) csum += (costA[r] * icn) * slv[r];
    RED_W(csum);
    if ((threadIdx.x & 63) == 0)
        atomicAdd(out, csum * (1.0f / (float)(BB * NN)));

    if (s == 0) {
        #pragma unroll
        for (int r = 0; r < R; ++r) {
            int gi = b * NN + n0 + r;
            float sa = fmaxf(satl[gi] - rd[r] * slv[r], 0.0f);
            satl[gi] = sa;
            sl[gi] = sa / (acc2[r] + 1e-9f);
        }
    }
}

// ---------- C-only pruned (level 2): satl update + cost, no A part ----------
#define C_COMP1(v, lw)                                           \
    { _Pragma("unroll")                                          \
      for (int r = 0; r < R; ++r) {                              \
        float a0 = (v).w + clpp[r];                              \
        float a1 = fmaf(zs[r], (v).z, a0);                       \
        float a2 = fmaf(ys[r], (v).y, a1);                       \
        float arg = fmaf(xs[r], (v).x, a2);                      \
        float t   = EXP2F(arg);                                  \
        rd[r] += t;                                              \
        c1[r] = fmaf(t, arg, c1[r]);                             \
        c2[r] = fmaf(t, (lw), c2[r]);                            \
      } }

__global__ __launch_bounds__(BLK, 2) void emd_passC_p(
        const float* __restrict__ xyz1, const float* __restrict__ xyz2,
        const float* __restrict__ sl, float* __restrict__ satl,
        const float* __restrict__ sr2, float* __restrict__ out,
        const float* __restrict__ rbb, const float* __restrict__ cbb,
        float cl, float T) {
    __shared__ float4 q[CHUNK];
    __shared__ float  qa[CHUNK];
    const int b    = blockIdx.x / (NN / RPB);
    const int tile = blockIdx.x % (NN / RPB);
    const float* x2b = xyz2 + (size_t)b * MM * 3;
    const float* s2b = sr2 + (size_t)b * MM;

    const int g = threadIdx.x / S, s = threadIdx.x % S;
    const int n0 = tile * RPB + g * R;
    const float* pp_ = xyz1 + ((size_t)b * NN + n0) * 3;
    const float m2cl = -2.0f * cl;
    const float icl  = 1.0f / cl;
    float xs[R], ys[R], zs[R], clpp[R], rd[R], c1[R], c2[R], slv[R];
    #pragma unroll
    for (int r = 0; r < R; ++r) {
        float x = pp_[3*r], y = pp_[3*r+1], z = pp_[3*r+2];
        clpp[r] = cl * (x*x + y*y + z*z);
        xs[r] = m2cl * x; ys[r] = m2cl * y; zs[r] = m2cl * z;
        rd[r] = 0.0f; c1[r] = 0.0f; c2[r] = 0.0f;
        slv[r] = sl[b * NN + n0 + r];
    }
    BOX_SETUP(rbb);

    for (int c0 = 0; c0 < MM; c0 += CHUNK) {
        __syncthreads();
        for (int m = threadIdx.x; m < CHUNK; m += BLK) {
            int mm = c0 + m;
            float xx = x2b[3*mm], yy = x2b[3*mm+1], zz = x2b[3*mm+2];
            float qq = xx*xx + yy*yy + zz*zz;
            float lw = LOG2F(fmaxf(s2b[mm], 1e-30f));
            q[m]  = make_float4(xx, yy, zz, fmaf(cl, qq, lw));
            qa[m] = lw;
        }
        __syncthreads();
        for (int gs = 0; gs < G; ++gs) {
            BOX_D2M(cbb, c0, gs, d2m);
            if (d2m > T) continue;
            #pragma unroll
            for (int k = 0; k < 4; ++k) {
                int idx = (gs*4 + k)*S + s;
                float4 v = q[idx]; float lw = qa[idx];
                C_COMP1(v, lw);
            }
        }
    }

    #pragma unroll
    for (int r = 0; r < R; ++r) { RED_S(rd[r]); }

    float csum = 0.0f;
    #pragma unroll
    for (int r = 0; r < R; ++r) csum += ((c1[r] - c2[r]) * icl) * slv[r];
    RED_W(csum);
    if ((threadIdx.x & 63) == 0)
        atomicAdd(out, csum * (1.0f / (float)(BB * NN)));

    if (s == 0) {
        #pragma unroll
        for (int r = 0; r < R; ++r) {
            int gi = b * NN + n0 + r;
            satl[gi] = fmaxf(satl[gi] - rd[r] * slv[r], 0.0f);
        }
    }
}

// ---------- Compact A (level 3): sl3 over compact rows x compact cols ----------
__global__ __launch_bounds__(BLK, 2) void emd_passA_c(
        float4* __restrict__ rowBuf, const int* __restrict__ rIdx,
        const int* __restrict__ rCnt, const float4* __restrict__ colBuf,
        const int* __restrict__ cCnt, const float* __restrict__ satl,
        float* __restrict__ sl, const float* __restrict__ rbbC,
        const float* __restrict__ cbbC, float c, float T) {
    __shared__ float4 q[CHUNK];
    const int b    = blockIdx.x / (NN / RPB);
    const int tile = blockIdx.x % (NN / RPB);
    const int Nc = rCnt[b], Mc = cCnt[b];
    if (tile * RPB >= Nc) return;
    const float4* cbp = colBuf + (size_t)b * MM;

    const int g = threadIdx.x / S, s = threadIdx.x % S;
    const int n0 = tile * RPB + g * R;
    const float m2c = -2.0f * c;
    float xs[R], ys[R], zs[R], cpp[R], acc[R];
    #pragma unroll
    for (int r = 0; r < R; ++r) {
        float4 rv = rowBuf[(size_t)b * NN + n0 + r];
        cpp[r] = c * (rv.x*rv.x + rv.y*rv.y + rv.z*rv.z);
        xs[r] = m2c * rv.x; ys[r] = m2c * rv.y; zs[r] = m2c * rv.z;
        acc[r] = 0.0f;
    }
    BOX_SETUP(rbbC);

    const int nch = (Mc + CHUNK - 1) / CHUNK;
    for (int ci = 0; ci < nch; ++ci) {
        const int c0 = ci * CHUNK;
        __syncthreads();
        for (int m = threadIdx.x; m < CHUNK; m += BLK) {
            int mm = c0 + m;
            if (mm < Mc) {
                float4 cv = cbp[mm];
                float qq = cv.x*cv.x + cv.y*cv.y + cv.z*cv.z;
                q[m] = make_float4(cv.x, cv.y, cv.z, fmaf(c, qq, LOG2F(cv.w)));
            } else {
                q[m] = make_float4(0.f, 0.f, 0.f, -1e30f);
            }
        }
        __syncthreads();
        int rem = Mc - c0; if (rem > CHUNK) rem = CHUNK;
        const int Gact = (rem + S*4 - 1) / (S*4);
        for (int gs = 0; gs < Gact; ++gs) {
            BOX_D2M(cbbC, c0, gs, d2m);
            if (d2m > T) continue;
            float4 va[4];
            AB_LOAD(va, gs);
            AB_COMP(va);
        }
    }
    #pragma unroll
    for (int r = 0; r < R; ++r) { RED_S(acc[r]); }
    if (s == 0) {
        #pragma unroll
        for (int r = 0; r < R; ++r) {
            if (n0 + r < Nc) {
                int gi = b * NN + rIdx[(size_t)b * NN + n0 + r];
                float v = satl[gi] / (acc[r] + 1e-9f);
                sl[gi] = v;
                ((float*)&rowBuf[(size_t)b * NN + n0 + r])[3] = v;
            }
        }
    }
}

// ---------- Compact Pass B (levels 3..8; PRUNE only at l=3) ----------
template<int PRUNE>
__global__ __launch_bounds__(BLK, 2) void emd_passB_c(
        const float4* __restrict__ colBuf, const int* __restrict__ cIdx,
        const int* __restrict__ cCnt, const float4* __restrict__ rowBuf,
        const int* __restrict__ rCnt, float* __restrict__ satr,
        float* __restrict__ sr2c, float* __restrict__ satrnc,
        float* __restrict__ bsum, const float* __restrict__ rbbC,
        const float* __restrict__ cbbC, int do_sum, float c, float T) {
    __shared__ float4 q[CHUNK];
    const int b    = blockIdx.x / (MM / RPB);
    const int tile = blockIdx.x % (MM / RPB);
    const int Mc = cCnt[b], Nc = rCnt[b];
    if (tile * RPB >= Mc) return;
    const float4* rb_ = rowBuf + (size_t)b * NN;

    const int g = threadIdx.x / S, s = threadIdx.x % S;
    const int m0 = tile * RPB + g * R;
    const float m2c = -2.0f * c;
    float xs[R], ys[R], zs[R], cpp[R], acc[R], srv[R];
    #pragma unroll
    for (int r = 0; r < R; ++r) {
        float4 cv = colBuf[(size_t)b * MM + m0 + r];
        srv[r] = cv.w;
        cpp[r] = c * (cv.x*cv.x + cv.y*cv.y + cv.z*cv.z);
        xs[r] = m2c * cv.x; ys[r] = m2c * cv.y; zs[r] = m2c * cv.z;
        acc[r] = 0.0f;
    }
    BOX_SETUP(rbbC);

    const int nch = (Nc + CHUNK - 1) / CHUNK;
    for (int ci = 0; ci < nch; ++ci) {
        const int c0 = ci * CHUNK;
        __syncthreads();
        for (int n = threadIdx.x; n < CHUNK; n += BLK) {
            int nn = c0 + n;
            if (nn < Nc) {
                float4 rv = rb_[nn];
                float pp = rv.x*rv.x + rv.y*rv.y + rv.z*rv.z;
                q[n] = make_float4(rv.x, rv.y, rv.z, fmaf(c, pp, LOG2F(rv.w)));
            } else {
                q[n] = make_float4(0.f, 0.f, 0.f, -1e30f);
            }
        }
        __syncthreads();
        int rem = Nc - c0; if (rem > CHUNK) rem = CHUNK;
        const int Gact = (rem + S*4 - 1) / (S*4);
        if (PRUNE) {
            for (int gs = 0; gs < Gact; ++gs) {
                BOX_D2M(cbbC, c0, gs, d2m);
                if (d2m > T) continue;
                float4 va[4];
                AB_LOAD(va, gs);
                AB_COMP(va);
            }
        } else {
            float4 va[4], vb[4];
            AB_LOAD(va, 0);
            #pragma unroll 1
            for (int gs = 0; gs < Gact; gs += 2) {
                if (gs + 1 < Gact) { AB_LOAD(vb, gs + 1); }
                AB_COMP(va);
                if (gs + 2 < Gact) { AB_LOAD(va, gs + 2); }
                if (gs + 1 < Gact) { AB_COMP(vb); }
            }
        }
    }
    #pragma unroll
    for (int r = 0; r < R; ++r) { RED_S(acc[r]); }
    float part = 0.0f;
    if (s == 0) {
        #pragma unroll
        for (int r = 0; r < R; ++r) {
            if (m0 + r < Mc) {
                float sr    = srv[r];
                float ss2   = acc[r] * sr;
                float ratio = fminf(sr / (ss2 + 1e-9f), 1.0f);
                float sn    = fmaxf(sr - ss2 * ratio, 0.0f);
                size_t ci2 = (size_t)b * MM + m0 + r;
                sr2c[ci2]   = sr * ratio;
                satrnc[ci2] = sn;
                satr[(size_t)b * MM + cIdx[ci2]] = sn;
                part += sn;
            }
        }
    }
    if (do_sum) {
        RED_W(part);
        if ((threadIdx.x & 63) == 0) atomicAdd(&bsum[b], part);
    }
}

// ---------- Compact fused C(l)+A(l+1) (levels 3..7; PRUNE only at l=3) ----------
template<int PRUNE>
__global__ __launch_bounds__(BLK, 2) void emd_passCA0_c(
        const float4* __restrict__ rowBuf, const int* __restrict__ rIdx,
        const int* __restrict__ rCnt, const float4* __restrict__ colBuf,
        const int* __restrict__ cCnt, const float* __restrict__ sr2c,
        const float* __restrict__ satrnc, float* __restrict__ satl,
        float* __restrict__ sl, float* __restrict__ out,
        const float* __restrict__ rbbC, const float* __restrict__ cbbC,
        float cl, float cn, float T, float TC) {
    __shared__ float4 q[CHUNK];
    __shared__ float2 w[CHUNK];
    const int b    = blockIdx.x / (NN / RPB);
    const int tile = blockIdx.x % (NN / RPB);
    const int Nc = rCnt[b], Mc = cCnt[b];
    if (tile * RPB >= Nc) return;
    const float4* cbp = colBuf + (size_t)b * MM;
    const float* s2p = sr2c + (size_t)b * MM;
    const float* snp = satrnc + (size_t)b * MM;

    const int g = threadIdx.x / S, s = threadIdx.x % S;
    const int n0 = tile * RPB + g * R;
    const float m2cn = -2.0f * cn;
    const float icn  = 1.0f / cn;
    float xs[R], ys[R], zs[R], cnpp[R], rd[R], costA[R], acc2[R], slv[R];
    #pragma unroll
    for (int r = 0; r < R; ++r) {
        float4 rv = rowBuf[(size_t)b * NN + n0 + r];
        slv[r] = rv.w;
        cnpp[r] = cn * (rv.x*rv.x + rv.y*rv.y + rv.z*rv.z);
        xs[r] = m2cn * rv.x; ys[r] = m2cn * rv.y; zs[r] = m2cn * rv.z;
        rd[r] = 0.0f; costA[r] = 0.0f; acc2[r] = 0.0f;
    }
    BOX_SETUP(rbbC);

    const int nch = (Mc + CHUNK - 1) / CHUNK;
    for (int ci = 0; ci < nch; ++ci) {
        const int c0 = ci * CHUNK;
        __syncthreads();
        for (int m = threadIdx.x; m < CHUNK; m += BLK) {
            int mm = c0 + m;
            if (mm < Mc) {
                float4 cv = cbp[mm];
                float qq = cv.x*cv.x + cv.y*cv.y + cv.z*cv.z;
                q[m] = make_float4(cv.x, cv.y, cv.z, cn * qq);
                w[m] = make_float2(s2p[mm], snp[mm]);
            } else {
                q[m] = make_float4(0.f, 0.f, 0.f, 0.f);
                w[m] = make_float2(0.f, 0.f);
            }
        }
        __syncthreads();
        int rem = Mc - c0; if (rem > CHUNK) rem = CHUNK;
        const int Gact = (rem + S*4 - 1) / (S*4);
        if (PRUNE) {
            for (int gs = 0; gs < Gact; ++gs) {
                BOX_D2M(cbbC, c0, gs, d2m);
                if (d2m > T) continue;
                float4 va[4]; float2 wa[4];
                CA0_LOAD(va, wa, gs);
                if (d2m > TC) {
                    CA0_COMP_AONLY(va, wa);
                } else {
                    CA0_COMP(va, wa);
                }
            }
        } else {
            float4 va[4], vb[4]; float2 wa[4], wb[4];
            CA0_LOAD(va, wa, 0);
            #pragma unroll 1
            for (int gs = 0; gs < Gact; gs += 2) {
                if (gs + 1 < Gact) { CA0_LOAD(vb, wb, gs + 1); }
                CA0_COMP(va, wa);
                if (gs + 2 < Gact) { CA0_LOAD(va, wa, gs + 2); }
                if (gs + 1 < Gact) { CA0_COMP(vb, wb); }
            }
        }
    }

    #pragma unroll
    for (int r = 0; r < R; ++r) { RED_S(rd[r]); RED_S(acc2[r]); }

    float csum = 0.0f;
    #pragma unroll
    for (int r = 0; r < R; ++r)
        csum += (n0 + r < Nc) ? (costA[r] * icn) * slv[r] : 0.0f;
    RED_W(csum);
    if ((threadIdx.x & 63) == 0)
        atomicAdd(out, csum * (1.0f / (float)(BB * NN)));

    if (s == 0) {
        #pragma unroll
        for (int r = 0; r < R; ++r) {
            if (n0 + r < Nc) {
                int gi = b * NN + rIdx[(size_t)b * NN + n0 + r];
                float sa = fmaxf(satl[gi] - rd[r] * slv[r], 0.0f);
                satl[gi] = sa;
                sl[gi] = sa / (acc2[r] + 1e-9f);
            }
        }
    }
}

// ---------- Compact fused C(8)+A(9) ----------
#define CA1_LOAD(vv, aa, gg)                                     \
    _Pragma("unroll")                                            \
    for (int k = 0; k < 4; ++k) {                                \
        int idx = ((gg)*4 + k)*S + s;                            \
        vv[k] = q[idx]; aa[k] = qa[idx];                         \
    }

#define CA1_COMP(vv, aa)                                         \
    _Pragma("unroll")                                            \
    for (int k = 0; k < 4; ++k) {                                \
        float4 v = vv[k]; float lw = aa[k];                      \
        _Pragma("unroll")                                        \
        for (int r = 0; r < R; ++r) {                            \
            float a0 = v.w + clpp[r];                            \
            float a1 = fmaf(zs[r], v.z, a0);                     \
            float a2 = fmaf(ys[r], v.y, a1);                     \
            float arg = fmaf(xs[r], v.x, a2);                    \
            float t   = EXP2F(arg);                              \
            rd[r] += t;                                          \
            c1[r] = fmaf(t, arg, c1[r]);                         \
            c2[r] = fmaf(t, lw, c2[r]);                          \
        }                                                        \
    }

__global__ __launch_bounds__(BLK, 2) void emd_passCA1_c(
        const float4* __restrict__ rowBuf, const int* __restrict__ rIdx,
        const int* __restrict__ rCnt, const float4* __restrict__ colBuf,
        const int* __restrict__ cCnt, const float* __restrict__ sr2c,
        float* __restrict__ satl, float* __restrict__ sl,
        const float* __restrict__ bsum, float* __restrict__ slsum,
        float* __restrict__ out, float cl) {
    __shared__ float4 q[CHUNK];
    __shared__ float  qa[CHUNK];
    const int b    = blockIdx.x / (NN / RPB);
    const int tile = blockIdx.x % (NN / RPB);
    const int Nc = rCnt[b], Mc = cCnt[b];
    if (tile * RPB >= Nc) return;
    const float4* cbp = colBuf + (size_t)b * MM;
    const float* s2p = sr2c + (size_t)b * MM;

    const int g = threadIdx.x / S, s = threadIdx.x % S;
    const int n0 = tile * RPB + g * R;
    const float m2cl = -2.0f * cl;
    const float icl  = 1.0f / cl;
    float xs[R], ys[R], zs[R], clpp[R], rd[R], c1[R], c2[R], slv[R];
    #pragma unroll
    for (int r = 0; r < R; ++r) {
        float4 rv = rowBuf[(size_t)b * NN + n0 + r];
        slv[r] = rv.w;
        clpp[r] = cl * (rv.x*rv.x + rv.y*rv.y + rv.z*rv.z);
        xs[r] = m2cl * rv.x; ys[r] = m2cl * rv.y; zs[r] = m2cl * rv.z;
        rd[r] = 0.0f; c1[r] = 0.0f; c2[r] = 0.0f;
    }

    const int nch = (Mc + CHUNK - 1) / CHUNK;
    for (int ci = 0; ci < nch; ++ci) {
        const int c0 = ci * CHUNK;
        __syncthreads();
        for (int m = threadIdx.x; m < CHUNK; m += BLK) {
            int mm = c0 + m;
            if (mm < Mc) {
                float4 cv = cbp[mm];
                float qq = cv.x*cv.x + cv.y*cv.y + cv.z*cv.z;
                float lw = LOG2F(fmaxf(s2p[mm], 1e-30f));
                q[m]  = make_float4(cv.x, cv.y, cv.z, fmaf(cl, qq, lw));
                qa[m] = lw;
            } else {
                q[m]  = make_float4(0.f, 0.f, 0.f, -1e30f);
                qa[m] = 0.f;
            }
        }
        __syncthreads();
        int rem = Mc - c0; if (rem > CHUNK) rem = CHUNK;
        const int Gact = (rem + S*4 - 1) / (S*4);
        float4 va[4], vb[4]; float aa[4], ab[4];
        CA1_LOAD(va, aa, 0);
        #pragma unroll 1
        for (int gs = 0; gs < Gact; gs += 2) {
            if (gs + 1 < Gact) { CA1_LOAD(vb, ab, gs + 1); }
            CA1_COMP(va, aa);
            if (gs + 2 < Gact) { CA1_LOAD(va, aa, gs + 2); }
            if (gs + 1 < Gact) { CA1_COMP(vb, ab); }
        }
    }

    #pragma unroll
    for (int r = 0; r < R; ++r) { RED_S(rd[r]); }

    float csum = 0.0f;
    #pragma unroll
    for (int r = 0; r < R; ++r)
        csum += (n0 + r < Nc) ? ((c1[r] - c2[r]) * icl) * slv[r] : 0.0f;
    RED_W(csum);
    if ((threadIdx.x & 63) == 0)
        atomicAdd(out, csum * (1.0f / (float)(BB * NN)));

    float part = 0.0f;
    if (s == 0) {
        float bs = bsum[b];
        #pragma unroll
        for (int r = 0; r < R; ++r) {
            if (n0 + r < Nc) {
                int gi = b * NN + rIdx[(size_t)b * NN + n0 + r];
                float sa = fmaxf(satl[gi] - rd[r] * slv[r], 0.0f);
                satl[gi] = sa;
                float s9 = sa / (bs + 1e-9f);
                sl[gi] = s9;
                part += s9;
            }
        }
    }
    RED_W(part);
    if ((threadIdx.x & 63) == 0) atomicAdd(&slsum[b], part);
}

// ---------- Level 9 (coef 0) closed form ----------
__global__ void emd_lvl9_col(const float* __restrict__ xyz2,
                             const float* __restrict__ satr,
                             const float* __restrict__ slsum,
                             float* __restrict__ scal) {
    int i = blockIdx.x * blockDim.x + threadIdx.x;
    int b = i / MM;
    const float* qp = xyz2 + (size_t)i * 3;
    float sr = satr[i];
    float ss2 = sr * slsum[b];
    float ratio = fminf(sr / (ss2 + 1e-9f), 1.0f);
    float s2 = sr * ratio;
    float x = qp[0], y = qp[1], z = qp[2];
    float v0 = s2, v1 = s2*x, v2 = s2*y, v3 = s2*z;
    float v4 = s2 * (x*x + y*y + z*z);
    #pragma unroll
    for (int d = 1; d < 64; d <<= 1) {
        v0 += __shfl_xor(v0, d); v1 += __shfl_xor(v1, d);
        v2 += __shfl_xor(v2, d); v3 += __shfl_xor(v3, d);
        v4 += __shfl_xor(v4, d);
    }
    if ((threadIdx.x & 63) == 0) {
        atomicAdd(&scal[b*5+0], v0); atomicAdd(&scal[b*5+1], v1);
        atomicAdd(&scal[b*5+2], v2); atomicAdd(&scal[b*5+3], v3);
        atomicAdd(&scal[b*5+4], v4);
    }
}

__global__ void emd_lvl9_cost(const float* __restrict__ xyz1,
                              const float* __restrict__ sl,
                              const float* __restrict__ scal,
                              float* __restrict__ out) {
    int i = blockIdx.x * blockDim.x + threadIdx.x;
    int b = i / NN;
    float W  = scal[b*5+0], Wx = scal[b*5+1], Wy = scal[b*5+2];
    float Wz = scal[b*5+3], Q  = scal[b*5+4];
    const float* p = xyz1 + (size_t)i * 3;
    float x = p[0], y = p[1], z = p[2];
    float pp = x*x + y*y + z*z;
    float dotw = x*Wx + y*Wy + z*Wz;
    float c = sl[i] * (pp * W + Q - 2.0f * dotw);
    #pragma unroll
    for (int d = 1; d < 64; d <<= 1) c += __shfl_xor(c, d);
    if ((threadIdx.x & 63) == 0)
        atomicAdd(out, c * (1.0f / (float)(BB * NN)));
}

extern "C" void kernel_launch(void* const* d_in, const int* in_sizes, int n_in,
                              void* d_out, int out_size, void* d_ws, size_t ws_size,
                              hipStream_t stream) {
    const float* xyz1 = (const float*)d_in[0];
    const float* xyz2 = (const float*)d_in[1];
    float* out  = (float*)d_out;

    float* satl   = (float*)d_ws;                // B*N
    float* sl     = satl  + BB * NN;             // B*N
    float* satr   = sl    + BB * NN;             // B*M
    float* sr2    = satr  + BB * MM;             // B*M (pruned levels)
    float* bsum   = sr2   + BB * MM;             // B
    float* slsum  = bsum  + BB;                  // B
    float* scal   = slsum + BB;                  // B*5
    float* xyz1s  = scal  + BB * 5;              // B*N*3
    float* xyz2s  = xyz1s + BB * NN * 3;         // B*M*3
    float* bb1_16 = xyz2s + BB * MM * 3;         // B*256*6
    float* bb1_64 = bb1_16 + BB * 256 * 6;       // B*64*6
    float* bb2_16 = bb1_64 + BB * 64 * 6;        // B*256*6
    float* bb2_64 = bb2_16 + BB * 256 * 6;       // B*64*6
    float4* rowBuf = (float4*)(bb2_64 + BB * 64 * 6); // B*N float4
    float4* colBuf = rowBuf + BB * NN;                // B*M float4
    float* sr2c   = (float*)(colBuf + BB * MM);  // B*M
    float* satrnc = sr2c  + BB * MM;             // B*M
    int*   rIdx   = (int*)(satrnc + BB * MM);    // B*N
    int*   cIdx   = rIdx  + BB * NN;             // B*M
    int*   rCnt   = cIdx  + BB * MM;             // B
    int*   cCnt   = rCnt  + BB;                  // B
    float* rb16c  = (float*)(cCnt + BB);         // B*256*6
    float* rb64c  = rb16c + BB * 256 * 6;        // B*64*6
    float* cb16c  = rb64c + BB * 64 * 6;         // B*256*6
    float* cb64c  = cb16c + BB * 256 * 6;        // B*64*6

    emd_sort<<<2 * BB, BLK, 0, stream>>>(xyz1, xyz2, xyz1s, xyz2s);
    emd_bbox_all<<<2 * (BB * 256 + BB * 64), 64, 0, stream>>>(
        xyz1s, xyz2s, bb1_16, bb1_64, bb2_16, bb2_64);
    emd_init<<<(BB * NN + 255) / 256, 256, 0, stream>>>(satl, satr, bsum,
                                                        slsum, scal, out);

    const double levels[10] = {-16384.0, -4096.0, -1024.0, -256.0, -64.0,
                               -16.0, -4.0, -1.0, -0.25, 0.0};
    const double LOG2E = 1.4426950408889634;
    float c[10], T[10];
    for (int l = 0; l < 10; ++l) {
        c[l] = (float)(levels[l] * LOG2E);
        T[l] = (l < 9) ? (float)(80.0 / (-levels[l] * LOG2E)) : 1e30f;
    }

    const int grid = BB * (NN / RPB);   // 512

    // levels 0..1: box-pruned full-array (dual-radius fused CA0)
    emd_passA_p<<<grid, BLK, 0, stream>>>(xyz1s, xyz2s, satl, satr, sl,
                                          bb1_16, bb2_64, c[0], T[0]);
    for (int l = 0; l <= 1; ++l) {
        emd_passB_p<<<grid, BLK, 0, stream>>>(xyz1s, xyz2s, sl, satr, sr2,
                                              bb2_16, bb1_64, c[l], T[l]);
        emd_passCA0_p<<<grid, BLK, 0, stream>>>(
            xyz1s, xyz2s, sl, satl, sr2, satr, out, bb1_16, bb2_64,
            c[l], c[l + 1], T[l + 1], T[l]);
    }
    // level 2: B + C-only (A(3) moves to compact domain)
    emd_passB_p<<<grid, BLK, 0, stream>>>(xyz1s, xyz2s, sl, satr, sr2,
                                          bb2_16, bb1_64, c[2], T[2]);
    emd_passC_p<<<grid, BLK, 0, stream>>>(xyz1s, xyz2s, sl, satl, sr2, out,
                                          bb1_16, bb2_64, c[2], T[2]);

    // compact + A(3) in compact domain
    compact_all<<<2 * BB, BLK, 0, stream>>>(xyz1s, xyz2s, satl, satr, sl,
                                            rowBuf, rIdx, rCnt,
                                            colBuf, cIdx, cCnt,
                                            rb16c, rb64c, cb16c, cb64c);
    emd_passA_c<<<grid, BLK, 0, stream>>>(rowBuf, rIdx, rCnt, colBuf, cCnt,
                                          satl, sl, rb16c, cb64c, c[3], T[3]);

    for (int l = 3; l <= 8; ++l) {
        if (l == 3)
            emd_passB_c<1><<<grid, BLK, 0, stream>>>(
                colBuf, cIdx, cCnt, rowBuf, rCnt, satr, sr2c, satrnc, bsum,
                cb16c, rb64c, 0, c[l], T[l]);
        else
            emd_passB_c<0><<<grid, BLK, 0, stream>>>(
                colBuf, cIdx, cCnt, rowBuf, rCnt, satr, sr2c, satrnc, bsum,
                cb16c, rb64c, (l == 8) ? 1 : 0, c[l], 1e30f);
        if (l < 8) {
            if (l == 3)
                emd_passCA0_c<1><<<grid, BLK, 0, stream>>>(
                    rowBuf, rIdx, rCnt, colBuf, cCnt, sr2c, satrnc,
                    satl, sl, out, rb16c, cb64c, c[l], c[l + 1],
                    T[l + 1], T[l]);
            else
                emd_passCA0_c<0><<<grid, BLK, 0, stream>>>(
                    rowBuf, rIdx, rCnt, colBuf, cCnt, sr2c, satrnc,
                    satl, sl, out, rb16c, cb64c, c[l], c[l + 1],
                    1e30f, 1e30f);
            compact_all<<<2 * BB, BLK, 0, stream>>>(xyz1s, xyz2s, satl, satr, sl,
                                                    rowBuf, rIdx, rCnt,
                                                    colBuf, cIdx, cCnt,
                                                    rb16c, rb64c, cb16c, cb64c);
        } else {
            emd_passCA1_c<<<grid, BLK, 0, stream>>>(
                rowBuf, rIdx, rCnt, colBuf, cCnt, sr2c,
                satl, sl, bsum, slsum, out, c[8]);
        }
    }
    emd_lvl9_col<<<BB * MM / 256, 256, 0, stream>>>(xyz2s, satr, slsum, scal);
    emd_lvl9_cost<<<BB * NN / 256, 256, 0, stream>>>(xyz1s, sl, scal, out);
}

// Round 16
// 754.373 us; speedup vs baseline: 1.0154x; 1.0154x over previous
//
#include <hip/hip_runtime.h>

// EMD approx-match (Fan et al. approxmatch.cu), B=8, N=M=4096.
// Level 0 only: box-pruned full-array sweeps (dual-radius fused C+A).
// Levels 1-8: active-set compaction (satl/satr > 1e-8) with branch-free
// pipelined compact-to-compact sweeps (work ~ Nc*Mc). Level 9 closed form.
// (R16: compact boundary moved from level 3 to level 1 — R13 kernels verbatim.)

#define BB 8
#define NN 4096
#define MM 4096
#define NPTS 4096

constexpr int   BLK   = 256;
constexpr int   S     = 16;
constexpr int   R     = 4;
constexpr int   RPB   = (BLK / S) * R;   // 64
constexpr int   CHUNK = 2048;
constexpr int   G     = (CHUNK / S) / 4; // 32 groups of 64 cols
constexpr float TAU   = 1e-8f;

#if defined(__has_builtin)
#if __has_builtin(__builtin_amdgcn_exp2f)
#define EXP2F(x) __builtin_amdgcn_exp2f(x)
#endif
#if __has_builtin(__builtin_amdgcn_logf)
#define LOG2F(x) __builtin_amdgcn_logf(x)
#endif
#endif
#ifndef EXP2F
#define EXP2F(x) exp2f(x)
#endif
#ifndef LOG2F
#define LOG2F(x) log2f(x)
#endif

// ---------- counting sort into 64 spatial cells (both clouds, one launch) ----------
__global__ void emd_sort(const float* __restrict__ x1, const float* __restrict__ x2,
                         float* __restrict__ s1, float* __restrict__ s2) {
    __shared__ int hist[64];
    __shared__ int cur[64];
    const int blk = blockIdx.x;
    const float* src = (blk < BB) ? x1 + (size_t)blk * NPTS * 3
                                  : x2 + (size_t)(blk - BB) * NPTS * 3;
    float* dst = (blk < BB) ? s1 + (size_t)blk * NPTS * 3
                            : s2 + (size_t)(blk - BB) * NPTS * 3;
    for (int i = threadIdx.x; i < 64; i += BLK) hist[i] = 0;
    __syncthreads();
    for (int i = threadIdx.x; i < NPTS; i += BLK) {
        float x = src[3*i], y = src[3*i+1], z = src[3*i+2];
        int cx = (int)(x * 4.0f); cx = cx < 0 ? 0 : (cx > 3 ? 3 : cx);
        int cy = (int)(y * 4.0f); cy = cy < 0 ? 0 : (cy > 3 ? 3 : cy);
        int cz = (int)(z * 4.0f); cz = cz < 0 ? 0 : (cz > 3 ? 3 : cz);
        atomicAdd(&hist[(cx << 4) | (cy << 2) | cz], 1);
    }
    __syncthreads();
    if (threadIdx.x == 0) {
        int acc = 0;
        for (int k = 0; k < 64; ++k) { cur[k] = acc; acc += hist[k]; }
    }
    __syncthreads();
    for (int i = threadIdx.x; i < NPTS; i += BLK) {
        float x = src[3*i], y = src[3*i+1], z = src[3*i+2];
        int cx = (int)(x * 4.0f); cx = cx < 0 ? 0 : (cx > 3 ? 3 : cx);
        int cy = (int)(y * 4.0f); cy = cy < 0 ? 0 : (cy > 3 ? 3 : cy);
        int cz = (int)(z * 4.0f); cz = cz < 0 ? 0 : (cz > 3 ? 3 : cz);
        int idx = atomicAdd(&cur[(cx << 4) | (cy << 2) | cz], 1);
        dst[3*idx] = x; dst[3*idx+1] = y; dst[3*idx+2] = z;
    }
}

// ---------- 16- and 64-point bboxes of sorted clouds, one launch ----------
__global__ void emd_bbox_all(const float* __restrict__ x1s,
                             const float* __restrict__ x2s,
                             float* __restrict__ bb1_16, float* __restrict__ bb1_64,
                             float* __restrict__ bb2_16, float* __restrict__ bb2_64) {
    const int PER = BB * 256 + BB * 64;   // per cloud
    int id = blockIdx.x;
    int cloud = id / PER, r = id % PER;
    const float* xs = cloud ? x2s : x1s;
    float* bb; int gp, grp;
    if (r < BB * 256) { gp = 16; grp = r; bb = cloud ? bb2_16 : bb1_16; }
    else             { gp = 64; grp = r - BB * 256; bb = cloud ? bb2_64 : bb1_64; }
    const int lane = threadIdx.x;
    float xlo = 1e30f, xhi = -1e30f, ylo = 1e30f, yhi = -1e30f,
          zlo = 1e30f, zhi = -1e30f;
    if (lane < gp) {
        const float* p = xs + ((size_t)grp * gp + lane) * 3;
        xlo = xhi = p[0]; ylo = yhi = p[1]; zlo = zhi = p[2];
    }
    #pragma unroll
    for (int d = 1; d < 64; d <<= 1) {
        xlo = fminf(xlo, __shfl_xor(xlo, d)); xhi = fmaxf(xhi, __shfl_xor(xhi, d));
        ylo = fminf(ylo, __shfl_xor(ylo, d)); yhi = fmaxf(yhi, __shfl_xor(yhi, d));
        zlo = fminf(zlo, __shfl_xor(zlo, d)); zhi = fmaxf(zhi, __shfl_xor(zhi, d));
    }
    if (lane == 0) {
        float* o = bb + (size_t)grp * 6;
        o[0]=xlo; o[1]=xhi; o[2]=ylo; o[3]=yhi; o[4]=zlo; o[5]=zhi;
    }
}

__global__ void emd_init(float* __restrict__ satl, float* __restrict__ satr,
                         float* __restrict__ bsum, float* __restrict__ slsum,
                         float* __restrict__ scal, float* __restrict__ out) {
    int i = blockIdx.x * blockDim.x + threadIdx.x;
    if (i < BB * NN) satl[i] = 1.0f;
    if (i < BB * MM) satr[i] = 1.0f;
    if (i < BB)      bsum[i] = 0.0f;
    if (i < BB)      slsum[i] = 0.0f;
    if (i < BB * 5)  scal[i] = 0.0f;
    if (i == 0)      out[0]  = 0.0f;
}

// ---------- merged active-set compaction: blocks 0..B-1 cols, B..2B-1 rows ----------
__global__ void compact_all(const float* __restrict__ xyz1s,
                            const float* __restrict__ xyz2s,
                            const float* __restrict__ satl,
                            const float* __restrict__ satr,
                            float* __restrict__ sl,
                            float4* __restrict__ rowBuf, int* __restrict__ rIdx,
                            int* __restrict__ rCnt,
                            float4* __restrict__ colBuf, int* __restrict__ cIdx,
                            int* __restrict__ cCnt) {
    __shared__ int cnts[BLK];
    const bool isRow = blockIdx.x >= BB;
    const int b = isRow ? (blockIdx.x - BB) : blockIdx.x;
    const int PER = NPTS / BLK;   // 16
    const float* sb = (isRow ? satl : satr) + (size_t)b * NPTS;
    const float* xb = (isRow ? xyz1s : xyz2s) + (size_t)b * NPTS * 3;
    float* slb = sl + (size_t)b * NN;
    const int st = threadIdx.x * PER;
    int c = 0;
    for (int i = 0; i < PER; ++i) c += (sb[st + i] > TAU) ? 1 : 0;
    cnts[threadIdx.x] = c;
    __syncthreads();
    for (int d = 1; d < BLK; d <<= 1) {
        int v = cnts[threadIdx.x];
        int u = (threadIdx.x >= d) ? cnts[threadIdx.x - d] : 0;
        __syncthreads();
        cnts[threadIdx.x] = v + u;
        __syncthreads();
    }
    const int total = cnts[BLK - 1];
    int off = cnts[threadIdx.x] - c;
    if (isRow) {
        for (int i = 0; i < PER; ++i) {
            int n = st + i;
            if (sb[n] > TAU) {
                rowBuf[(size_t)b * NN + off] =
                    make_float4(xb[3*n], xb[3*n+1], xb[3*n+2], slb[n]);
                rIdx[(size_t)b * NN + off] = n;
                ++off;
            } else if (slb[n] != 0.0f) {
                slb[n] = 0.0f;   // kill stale sl for level-9 closed form
            }
        }
        for (int i = total + threadIdx.x; i < NN; i += BLK) {
            rowBuf[(size_t)b * NN + i] = make_float4(0.f, 0.f, 0.f, 0.f);
            rIdx[(size_t)b * NN + i] = 0;
        }
        if (threadIdx.x == 0) rCnt[b] = total;
    } else {
        for (int i = 0; i < PER; ++i) {
            int m = st + i;
            if (sb[m] > TAU) {
                colBuf[(size_t)b * MM + off] =
                    make_float4(xb[3*m], xb[3*m+1], xb[3*m+2], sb[m]);
                cIdx[(size_t)b * MM + off] = m;
                ++off;
            }
        }
        for (int i = total + threadIdx.x; i < MM; i += BLK) {
            colBuf[(size_t)b * MM + i] = make_float4(0.f, 0.f, 0.f, 0.f);
            cIdx[(size_t)b * MM + i] = 0;
        }
        if (threadIdx.x == 0) cCnt[b] = total;
    }
}

// ---------- shared macros ----------
#define AB_LOAD(vv, gg)                                          \
    _Pragma("unroll")                                            \
    for (int k = 0; k < 4; ++k) vv[k] = q[((gg)*4 + k)*S + s];

#define AB_COMP(vv)                                              \
    _Pragma("unroll")                                            \
    for (int k = 0; k < 4; ++k) {                                \
        float4 v = vv[k];                                        \
        _Pragma("unroll")                                        \
        for (int r = 0; r < R; ++r) {                            \
            float a0 = v.w + cpp[r];                             \
            float a1 = fmaf(zs[r], v.z, a0);                     \
            float a2 = fmaf(ys[r], v.y, a1);                     \
            float arg = fmaf(xs[r], v.x, a2);                    \
            acc[r] += EXP2F(arg);                                \
        }                                                        \
    }

#define RED_S(v)                                                 \
    v += __shfl_xor(v, 1);  v += __shfl_xor(v, 2);               \
    v += __shfl_xor(v, 4);  v += __shfl_xor(v, 8);

#define RED_W(v)                                                 \
    v += __shfl_xor(v, 1);  v += __shfl_xor(v, 2);               \
    v += __shfl_xor(v, 4);  v += __shfl_xor(v, 8);               \
    v += __shfl_xor(v, 16); v += __shfl_xor(v, 32);

#define BOX_SETUP(rbb)                                           \
    const float* rb = (rbb) + (size_t)(b * 256 + tile * 4 + (threadIdx.x >> 6)) * 6; \
    const float rx0 = rb[0], rx1 = rb[1], ry0 = rb[2], ry1 = rb[3], \
                rz0 = rb[4], rz1 = rb[5];

#define BOX_D2M(cbb, c0, gs, d2m)                                \
    const float* cb = (cbb) + (size_t)(b * 64 + ((c0) >> 6) + (gs)) * 6; \
    float gx = fmaxf(0.0f, fmaxf(cb[0] - rx1, rx0 - cb[1]));     \
    float gy = fmaxf(0.0f, fmaxf(cb[2] - ry1, ry0 - cb[3]));     \
    float gz = fmaxf(0.0f, fmaxf(cb[4] - rz1, rz0 - cb[5]));     \
    float d2m = fmaf(gx, gx, fmaf(gy, gy, gz * gz));

// ---------- Pass A (level 0, pruned) ----------
__global__ __launch_bounds__(BLK, 2) void emd_passA_p(
        const float* __restrict__ xyz1, const float* __restrict__ xyz2,
        const float* __restrict__ satl, const float* __restrict__ satr,
        float* __restrict__ sl, const float* __restrict__ rbb,
        const float* __restrict__ cbb, float c, float T) {
    __shared__ float4 q[CHUNK];
    const int b    = blockIdx.x / (NN / RPB);
    const int tile = blockIdx.x % (NN / RPB);
    const float* x2b = xyz2 + (size_t)b * MM * 3;
    const float* srb = satr + (size_t)b * MM;

    const int g = threadIdx.x / S, s = threadIdx.x % S;
    const int n0 = tile * RPB + g * R;
    const float* p = xyz1 + ((size_t)b * NN + n0) * 3;
    const float m2c = -2.0f * c;
    float xs[R], ys[R], zs[R], cpp[R], acc[R];
    #pragma unroll
    for (int r = 0; r < R; ++r) {
        float x = p[3*r], y = p[3*r+1], z = p[3*r+2];
        cpp[r] = c * (x*x + y*y + z*z);
        xs[r] = m2c * x; ys[r] = m2c * y; zs[r] = m2c * z;
        acc[r] = 0.0f;
    }
    BOX_SETUP(rbb);

    for (int c0 = 0; c0 < MM; c0 += CHUNK) {
        __syncthreads();
        for (int m = threadIdx.x; m < CHUNK; m += BLK) {
            int mm = c0 + m;
            float xx = x2b[3*mm], yy = x2b[3*mm+1], zz = x2b[3*mm+2];
            float qq = xx*xx + yy*yy + zz*zz;
            q[m] = make_float4(xx, yy, zz, fmaf(c, qq, LOG2F(srb[mm])));
        }
        __syncthreads();
        for (int gs = 0; gs < G; ++gs) {
            BOX_D2M(cbb, c0, gs, d2m);
            if (d2m > T) continue;
            float4 va[4];
            AB_LOAD(va, gs);
            AB_COMP(va);
        }
    }
    #pragma unroll
    for (int r = 0; r < R; ++r) { RED_S(acc[r]); }
    if (s == 0) {
        #pragma unroll
        for (int r = 0; r < R; ++r) {
            int gi = b * NN + n0 + r;
            sl[gi] = satl[gi] / (acc[r] + 1e-9f);
        }
    }
}

// ---------- Pass B (level 0, pruned, full arrays) ----------
__global__ __launch_bounds__(BLK, 2) void emd_passB_p(
        const float* __restrict__ xyz1, const float* __restrict__ xyz2,
        const float* __restrict__ sl, float* __restrict__ satr,
        float* __restrict__ sr2, const float* __restrict__ rbb,
        const float* __restrict__ cbb, float c, float T) {
    __shared__ float4 q[CHUNK];
    const int b    = blockIdx.x / (MM / RPB);
    const int tile = blockIdx.x % (MM / RPB);
    const float* x1b = xyz1 + (size_t)b * NN * 3;
    const float* slb = sl + (size_t)b * NN;

    const int g = threadIdx.x / S, s = threadIdx.x % S;
    const int m0 = tile * RPB + g * R;
    const float* qp = xyz2 + ((size_t)b * MM + m0) * 3;
    const float m2c = -2.0f * c;
    float xs[R], ys[R], zs[R], cpp[R], acc[R];
    #pragma unroll
    for (int r = 0; r < R; ++r) {
        float x = qp[3*r], y = qp[3*r+1], z = qp[3*r+2];
        cpp[r] = c * (x*x + y*y + z*z);
        xs[r] = m2c * x; ys[r] = m2c * y; zs[r] = m2c * z;
        acc[r] = 0.0f;
    }
    BOX_SETUP(rbb);

    for (int c0 = 0; c0 < NN; c0 += CHUNK) {
        __syncthreads();
        for (int n = threadIdx.x; n < CHUNK; n += BLK) {
            int nn = c0 + n;
            float xx = x1b[3*nn], yy = x1b[3*nn+1], zz = x1b[3*nn+2];
            float pp = xx*xx + yy*yy + zz*zz;
            q[n] = make_float4(xx, yy, zz, fmaf(c, pp, LOG2F(slb[nn])));
        }
        __syncthreads();
        for (int gs = 0; gs < G; ++gs) {
            BOX_D2M(cbb, c0, gs, d2m);
            if (d2m > T) continue;
            float4 va[4];
            AB_LOAD(va, gs);
            AB_COMP(va);
        }
    }
    #pragma unroll
    for (int r = 0; r < R; ++r) { RED_S(acc[r]); }
    if (s == 0) {
        #pragma unroll
        for (int r = 0; r < R; ++r) {
            int gi = b * MM + m0 + r;
            float sr    = satr[gi];
            float ss2   = acc[r] * sr;
            float ratio = fminf(sr / (ss2 + 1e-9f), 1.0f);
            float sn    = fmaxf(sr - ss2 * ratio, 0.0f);
            sr2[gi]  = sr * ratio;
            satr[gi] = sn;
        }
    }
}

// ---------- Fused C(0)+A(1), dual-radius pruned ----------
#define CA0_LOAD(vv, ww, gg)                                     \
    _Pragma("unroll")                                            \
    for (int k = 0; k < 4; ++k) {                                \
        int idx = ((gg)*4 + k)*S + s;                            \
        vv[k] = q[idx]; ww[k] = w[idx];                          \
    }

#define CA0_COMP(vv, ww)                                         \
    _Pragma("unroll")                                            \
    for (int k = 0; k < 4; ++k) {                                \
        float4 v = vv[k]; float2 wv = ww[k];                     \
        _Pragma("unroll")                                        \
        for (int r = 0; r < R; ++r) {                            \
            float a0 = v.w + cnpp[r];                            \
            float a1 = fmaf(zs[r], v.z, a0);                     \
            float a2 = fmaf(ys[r], v.y, a1);                     \
            float arg = fmaf(xs[r], v.x, a2);                    \
            float en  = EXP2F(arg);                              \
            acc2[r] = fmaf(en, wv.y, acc2[r]);                   \
            float e2 = en * en;                                  \
            float t  = (e2 * e2) * wv.x;                         \
            rd[r]   += t;                                        \
            costA[r] = fmaf(t, arg, costA[r]);                   \
        }                                                        \
    }

// A-only body: C terms < 2^-80 in this annulus (d2m > TC)
#define CA0_COMP_AONLY(vv, ww)                                   \
    _Pragma("unroll")                                            \
    for (int k = 0; k < 4; ++k) {                                \
        float4 v = vv[k]; float2 wv = ww[k];                     \
        _Pragma("unroll")                                        \
        for (int r = 0; r < R; ++r) {                            \
            float a0 = v.w + cnpp[r];                            \
            float a1 = fmaf(zs[r], v.z, a0);                     \
            float a2 = fmaf(ys[r], v.y, a1);                     \
            float arg = fmaf(xs[r], v.x, a2);                    \
            float en  = EXP2F(arg);                              \
            acc2[r] = fmaf(en, wv.y, acc2[r]);                   \
        }                                                        \
    }

__global__ __launch_bounds__(BLK, 2) void emd_passCA0_p(
        const float* __restrict__ xyz1, const float* __restrict__ xyz2,
        float* __restrict__ sl, float* __restrict__ satl,
        const float* __restrict__ sr2, const float* __restrict__ satr_next,
        float* __restrict__ out, const float* __restrict__ rbb,
        const float* __restrict__ cbb, float cl, float cn,
        float T, float TC) {
    __shared__ float4 q[CHUNK];
    __shared__ float2 w[CHUNK];
    const int b    = blockIdx.x / (NN / RPB);
    const int tile = blockIdx.x % (NN / RPB);
    const float* x2b = xyz2 + (size_t)b * MM * 3;
    const float* s2b = sr2 + (size_t)b * MM;
    const float* srb = satr_next + (size_t)b * MM;

    const int g = threadIdx.x / S, s = threadIdx.x % S;
    const int n0 = tile * RPB + g * R;
    const float* pp_ = xyz1 + ((size_t)b * NN + n0) * 3;
    const float m2cn = -2.0f * cn;
    const float icn  = 1.0f / cn;
    float xs[R], ys[R], zs[R], cnpp[R], rd[R], costA[R], acc2[R], slv[R];
    #pragma unroll
    for (int r = 0; r < R; ++r) {
        float x = pp_[3*r], y = pp_[3*r+1], z = pp_[3*r+2];
        cnpp[r] = cn * (x*x + y*y + z*z);
        xs[r] = m2cn * x; ys[r] = m2cn * y; zs[r] = m2cn * z;
        rd[r] = 0.0f; costA[r] = 0.0f; acc2[r] = 0.0f;
        slv[r] = sl[b * NN + n0 + r];
    }
    BOX_SETUP(rbb);

    for (int c0 = 0; c0 < MM; c0 += CHUNK) {
        __syncthreads();
        for (int m = threadIdx.x; m < CHUNK; m += BLK) {
            int mm = c0 + m;
            float xx = x2b[3*mm], yy = x2b[3*mm+1], zz = x2b[3*mm+2];
            float qq = xx*xx + yy*yy + zz*zz;
            q[m] = make_float4(xx, yy, zz, cn * qq);
            w[m] = make_float2(s2b[mm], srb[mm]);
        }
        __syncthreads();
        for (int gs = 0; gs < G; ++gs) {
            BOX_D2M(cbb, c0, gs, d2m);
            if (d2m > T) continue;
            float4 va[4]; float2 wa[4];
            CA0_LOAD(va, wa, gs);
            if (d2m > TC) {
                CA0_COMP_AONLY(va, wa);
            } else {
                CA0_COMP(va, wa);
            }
        }
    }

    #pragma unroll
    for (int r = 0; r < R; ++r) { RED_S(rd[r]); RED_S(acc2[r]); }

    float csum = 0.0f;
    #pragma unroll
    for (int r = 0; r < R; ++r) csum += (costA[r] * icn) * slv[r];
    RED_W(csum);
    if ((threadIdx.x & 63) == 0)
        atomicAdd(out, csum * (1.0f / (float)(BB * NN)));

    if (s == 0) {
        #pragma unroll
        for (int r = 0; r < R; ++r) {
            int gi = b * NN + n0 + r;
            float sa = fmaxf(satl[gi] - rd[r] * slv[r], 0.0f);
            satl[gi] = sa;
            sl[gi] = sa / (acc2[r] + 1e-9f);
        }
    }
}

// ---------- Compact Pass B (levels 1..8) ----------
__global__ __launch_bounds__(BLK, 2) void emd_passB_c(
        const float4* __restrict__ colBuf, const int* __restrict__ cIdx,
        const int* __restrict__ cCnt, const float4* __restrict__ rowBuf,
        const int* __restrict__ rCnt, float* __restrict__ satr,
        float* __restrict__ sr2c, float* __restrict__ satrnc,
        float* __restrict__ bsum, int do_sum, float c) {
    __shared__ float4 q[CHUNK];
    const int b    = blockIdx.x / (MM / RPB);
    const int tile = blockIdx.x % (MM / RPB);
    const int Mc = cCnt[b], Nc = rCnt[b];
    if (tile * RPB >= Mc) return;
    const float4* rb = rowBuf + (size_t)b * NN;

    const int g = threadIdx.x / S, s = threadIdx.x % S;
    const int m0 = tile * RPB + g * R;
    const float m2c = -2.0f * c;
    float xs[R], ys[R], zs[R], cpp[R], acc[R], srv[R];
    #pragma unroll
    for (int r = 0; r < R; ++r) {
        float4 cv = colBuf[(size_t)b * MM + m0 + r];
        srv[r] = cv.w;
        cpp[r] = c * (cv.x*cv.x + cv.y*cv.y + cv.z*cv.z);
        xs[r] = m2c * cv.x; ys[r] = m2c * cv.y; zs[r] = m2c * cv.z;
        acc[r] = 0.0f;
    }

    const int nch = (Nc + CHUNK - 1) / CHUNK;
    for (int ci = 0; ci < nch; ++ci) {
        const int c0 = ci * CHUNK;
        __syncthreads();
        for (int n = threadIdx.x; n < CHUNK; n += BLK) {
            int nn = c0 + n;
            if (nn < Nc) {
                float4 rv = rb[nn];
                float pp = rv.x*rv.x + rv.y*rv.y + rv.z*rv.z;
                q[n] = make_float4(rv.x, rv.y, rv.z, fmaf(c, pp, LOG2F(rv.w)));
            } else {
                q[n] = make_float4(0.f, 0.f, 0.f, -1e30f);
            }
        }
        __syncthreads();
        int rem = Nc - c0; if (rem > CHUNK) rem = CHUNK;
        const int Gact = (rem + S*4 - 1) / (S*4);
        float4 va[4], vb[4];
        AB_LOAD(va, 0);
        #pragma unroll 1
        for (int gs = 0; gs < Gact; gs += 2) {
            if (gs + 1 < Gact) { AB_LOAD(vb, gs + 1); }
            AB_COMP(va);
            if (gs + 2 < Gact) { AB_LOAD(va, gs + 2); }
            if (gs + 1 < Gact) { AB_COMP(vb); }
        }
    }
    #pragma unroll
    for (int r = 0; r < R; ++r) { RED_S(acc[r]); }
    float part = 0.0f;
    if (s == 0) {
        #pragma unroll
        for (int r = 0; r < R; ++r) {
            if (m0 + r < Mc) {
                float sr    = srv[r];
                float ss2   = acc[r] * sr;
                float ratio = fminf(sr / (ss2 + 1e-9f), 1.0f);
                float sn    = fmaxf(sr - ss2 * ratio, 0.0f);
                size_t ci2 = (size_t)b * MM + m0 + r;
                sr2c[ci2]   = sr * ratio;
                satrnc[ci2] = sn;
                satr[(size_t)b * MM + cIdx[ci2]] = sn;
                part += sn;
            }
        }
    }
    if (do_sum) {
        RED_W(part);
        if ((threadIdx.x & 63) == 0) atomicAdd(&bsum[b], part);
    }
}

// ---------- Compact fused C(l)+A(l+1) (levels 1..7) ----------
__global__ __launch_bounds__(BLK, 2) void emd_passCA0_c(
        const float4* __restrict__ rowBuf, const int* __restrict__ rIdx,
        const int* __restrict__ rCnt, const float4* __restrict__ colBuf,
        const int* __restrict__ cCnt, const float* __restrict__ sr2c,
        const float* __restrict__ satrnc, float* __restrict__ satl,
        float* __restrict__ sl, float* __restrict__ out, float cl, float cn) {
    __shared__ float4 q[CHUNK];
    __shared__ float2 w[CHUNK];
    const int b    = blockIdx.x / (NN / RPB);
    const int tile = blockIdx.x % (NN / RPB);
    const int Nc = rCnt[b], Mc = cCnt[b];
    if (tile * RPB >= Nc) return;
    const float4* cbp = colBuf + (size_t)b * MM;
    const float* s2p = sr2c + (size_t)b * MM;
    const float* snp = satrnc + (size_t)b * MM;

    const int g = threadIdx.x / S, s = threadIdx.x % S;
    const int n0 = tile * RPB + g * R;
    const float m2cn = -2.0f * cn;
    const float icn  = 1.0f / cn;
    float xs[R], ys[R], zs[R], cnpp[R], rd[R], costA[R], acc2[R], slv[R];
    #pragma unroll
    for (int r = 0; r < R; ++r) {
        float4 rv = rowBuf[(size_t)b * NN + n0 + r];
        slv[r] = rv.w;
        cnpp[r] = cn * (rv.x*rv.x + rv.y*rv.y + rv.z*rv.z);
        xs[r] = m2cn * rv.x; ys[r] = m2cn * rv.y; zs[r] = m2cn * rv.z;
        rd[r] = 0.0f; costA[r] = 0.0f; acc2[r] = 0.0f;
    }

    const int nch = (Mc + CHUNK - 1) / CHUNK;
    for (int ci = 0; ci < nch; ++ci) {
        const int c0 = ci * CHUNK;
        __syncthreads();
        for (int m = threadIdx.x; m < CHUNK; m += BLK) {
            int mm = c0 + m;
            if (mm < Mc) {
                float4 cv = cbp[mm];
                float qq = cv.x*cv.x + cv.y*cv.y + cv.z*cv.z;
                q[m] = make_float4(cv.x, cv.y, cv.z, cn * qq);
                w[m] = make_float2(s2p[mm], snp[mm]);
            } else {
                q[m] = make_float4(0.f, 0.f, 0.f, 0.f);
                w[m] = make_float2(0.f, 0.f);
            }
        }
        __syncthreads();
        int rem = Mc - c0; if (rem > CHUNK) rem = CHUNK;
        const int Gact = (rem + S*4 - 1) / (S*4);
        float4 va[4], vb[4]; float2 wa[4], wb[4];
        CA0_LOAD(va, wa, 0);
        #pragma unroll 1
        for (int gs = 0; gs < Gact; gs += 2) {
            if (gs + 1 < Gact) { CA0_LOAD(vb, wb, gs + 1); }
            CA0_COMP(va, wa);
            if (gs + 2 < Gact) { CA0_LOAD(va, wa, gs + 2); }
            if (gs + 1 < Gact) { CA0_COMP(vb, wb); }
        }
    }

    #pragma unroll
    for (int r = 0; r < R; ++r) { RED_S(rd[r]); RED_S(acc2[r]); }

    float csum = 0.0f;
    #pragma unroll
    for (int r = 0; r < R; ++r) csum += (costA[r] * icn) * slv[r];
    RED_W(csum);
    if ((threadIdx.x & 63) == 0)
        atomicAdd(out, csum * (1.0f / (float)(BB * NN)));

    if (s == 0) {
        #pragma unroll
        for (int r = 0; r < R; ++r) {
            if (n0 + r < Nc) {
                int gi = b * NN + rIdx[(size_t)b * NN + n0 + r];
                float sa = fmaxf(satl[gi] - rd[r] * slv[r], 0.0f);
                satl[gi] = sa;
                sl[gi] = sa / (acc2[r] + 1e-9f);
            }
        }
    }
}

// ---------- Compact fused C(8)+A(9) ----------
#define CA1_LOAD(vv, aa, gg)                                     \
    _Pragma("unroll")                                            \
    for (int k = 0; k < 4; ++k) {                                \
        int idx = ((gg)*4 + k)*S + s;                            \
        vv[k] = q[idx]; aa[k] = qa[idx];                         \
    }

#define CA1_COMP(vv, aa)                                         \
    _Pragma("unroll")                                            \
    for (int k = 0; k < 4; ++k) {                                \
        float4 v = vv[k]; float lw = aa[k];                      \
        _Pragma("unroll")                                        \
        for (int r = 0; r < R; ++r) {                            \
            float a0 = v.w + clpp[r];                            \
            float a1 = fmaf(zs[r], v.z, a0);                     \
            float a2 = fmaf(ys[r], v.y, a1);                     \
            float arg = fmaf(xs[r], v.x, a2);                    \
            float t   = EXP2F(arg);                              \
            rd[r] += t;                                          \
            c1[r] = fmaf(t, arg, c1[r]);                         \
            c2[r] = fmaf(t, lw, c2[r]);                          \
        }                                                        \
    }

__global__ __launch_bounds__(BLK, 2) void emd_passCA1_c(
        const float4* __restrict__ rowBuf, const int* __restrict__ rIdx,
        const int* __restrict__ rCnt, const float4* __restrict__ colBuf,
        const int* __restrict__ cCnt, const float* __restrict__ sr2c,
        float* __restrict__ satl, float* __restrict__ sl,
        const float* __restrict__ bsum, float* __restrict__ slsum,
        float* __restrict__ out, float cl) {
    __shared__ float4 q[CHUNK];
    __shared__ float  qa[CHUNK];
    const int b    = blockIdx.x / (NN / RPB);
    const int tile = blockIdx.x % (NN / RPB);
    const int Nc = rCnt[b], Mc = cCnt[b];
    if (tile * RPB >= Nc) return;
    const float4* cbp = colBuf + (size_t)b * MM;
    const float* s2p = sr2c + (size_t)b * MM;

    const int g = threadIdx.x / S, s = threadIdx.x % S;
    const int n0 = tile * RPB + g * R;
    const float m2cl = -2.0f * cl;
    const float icl  = 1.0f / cl;
    float xs[R], ys[R], zs[R], clpp[R], rd[R], c1[R], c2[R], slv[R];
    #pragma unroll
    for (int r = 0; r < R; ++r) {
        float4 rv = rowBuf[(size_t)b * NN + n0 + r];
        slv[r] = rv.w;
        clpp[r] = cl * (rv.x*rv.x + rv.y*rv.y + rv.z*rv.z);
        xs[r] = m2cl * rv.x; ys[r] = m2cl * rv.y; zs[r] = m2cl * rv.z;
        rd[r] = 0.0f; c1[r] = 0.0f; c2[r] = 0.0f;
    }

    const int nch = (Mc + CHUNK - 1) / CHUNK;
    for (int ci = 0; ci < nch; ++ci) {
        const int c0 = ci * CHUNK;
        __syncthreads();
        for (int m = threadIdx.x; m < CHUNK; m += BLK) {
            int mm = c0 + m;
            if (mm < Mc) {
                float4 cv = cbp[mm];
                float qq = cv.x*cv.x + cv.y*cv.y + cv.z*cv.z;
                float lw = LOG2F(fmaxf(s2p[mm], 1e-30f));
                q[m]  = make_float4(cv.x, cv.y, cv.z, fmaf(cl, qq, lw));
                qa[m] = lw;
            } else {
                q[m]  = make_float4(0.f, 0.f, 0.f, -1e30f);
                qa[m] = 0.f;
            }
        }
        __syncthreads();
        int rem = Mc - c0; if (rem > CHUNK) rem = CHUNK;
        const int Gact = (rem + S*4 - 1) / (S*4);
        float4 va[4], vb[4]; float aa[4], ab[4];
        CA1_LOAD(va, aa, 0);
        #pragma unroll 1
        for (int gs = 0; gs < Gact; gs += 2) {
            if (gs + 1 < Gact) { CA1_LOAD(vb, ab, gs + 1); }
            CA1_COMP(va, aa);
            if (gs + 2 < Gact) { CA1_LOAD(va, aa, gs + 2); }
            if (gs + 1 < Gact) { CA1_COMP(vb, ab); }
        }
    }

    #pragma unroll
    for (int r = 0; r < R; ++r) { RED_S(rd[r]); }

    float csum = 0.0f;
    #pragma unroll
    for (int r = 0; r < R; ++r) csum += ((c1[r] - c2[r]) * icl) * slv[r];
    RED_W(csum);
    if ((threadIdx.x & 63) == 0)
        atomicAdd(out, csum * (1.0f / (float)(BB * NN)));

    float part = 0.0f;
    if (s == 0) {
        float bs = bsum[b];
        #pragma unroll
        for (int r = 0; r < R; ++r) {
            if (n0 + r < Nc) {
                int gi = b * NN + rIdx[(size_t)b * NN + n0 + r];
                float sa = fmaxf(satl[gi] - rd[r] * slv[r], 0.0f);
                satl[gi] = sa;
                float s9 = sa / (bs + 1e-9f);
                sl[gi] = s9;
                part += s9;
            }
        }
    }
    RED_W(part);
    if ((threadIdx.x & 63) == 0) atomicAdd(&slsum[b], part);
}

// ---------- Level 9 (coef 0) closed form ----------
__global__ void emd_lvl9_col(const float* __restrict__ xyz2,
                             const float* __restrict__ satr,
                             const float* __restrict__ slsum,
                             float* __restrict__ scal) {
    int i = blockIdx.x * blockDim.x + threadIdx.x;
    int b = i / MM;
    const float* qp = xyz2 + (size_t)i * 3;
    float sr = satr[i];
    float ss2 = sr * slsum[b];
    float ratio = fminf(sr / (ss2 + 1e-9f), 1.0f);
    float s2 = sr * ratio;
    float x = qp[0], y = qp[1], z = qp[2];
    float v0 = s2, v1 = s2*x, v2 = s2*y, v3 = s2*z;
    float v4 = s2 * (x*x + y*y + z*z);
    #pragma unroll
    for (int d = 1; d < 64; d <<= 1) {
        v0 += __shfl_xor(v0, d); v1 += __shfl_xor(v1, d);
        v2 += __shfl_xor(v2, d); v3 += __shfl_xor(v3, d);
        v4 += __shfl_xor(v4, d);
    }
    if ((threadIdx.x & 63) == 0) {
        atomicAdd(&scal[b*5+0], v0); atomicAdd(&scal[b*5+1], v1);
        atomicAdd(&scal[b*5+2], v2); atomicAdd(&scal[b*5+3], v3);
        atomicAdd(&scal[b*5+4], v4);
    }
}

__global__ void emd_lvl9_cost(const float* __restrict__ xyz1,
                              const float* __restrict__ sl,
                              const float* __restrict__ scal,
                              float* __restrict__ out) {
    int i = blockIdx.x * blockDim.x + threadIdx.x;
    int b = i / NN;
    float W  = scal[b*5+0], Wx = scal[b*5+1], Wy = scal[b*5+2];
    float Wz = scal[b*5+3], Q  = scal[b*5+4];
    const float* p = xyz1 + (size_t)i * 3;
    float x = p[0], y = p[1], z = p[2];
    float pp = x*x + y*y + z*z;
    float dotw = x*Wx + y*Wy + z*Wz;
    float c = sl[i] * (pp * W + Q - 2.0f * dotw);
    #pragma unroll
    for (int d = 1; d < 64; d <<= 1) c += __shfl_xor(c, d);
    if ((threadIdx.x & 63) == 0)
        atomicAdd(out, c * (1.0f / (float)(BB * NN)));
}

extern "C" void kernel_launch(void* const* d_in, const int* in_sizes, int n_in,
                              void* d_out, int out_size, void* d_ws, size_t ws_size,
                              hipStream_t stream) {
    const float* xyz1 = (const float*)d_in[0];
    const float* xyz2 = (const float*)d_in[1];
    float* out  = (float*)d_out;

    float* satl   = (float*)d_ws;                // B*N
    float* sl     = satl  + BB * NN;             // B*N
    float* satr   = sl    + BB * NN;             // B*M
    float* sr2    = satr  + BB * MM;             // B*M (level 0)
    float* bsum   = sr2   + BB * MM;             // B
    float* slsum  = bsum  + BB;                  // B
    float* scal   = slsum + BB;                  // B*5
    float* xyz1s  = scal  + BB * 5;              // B*N*3
    float* xyz2s  = xyz1s + BB * NN * 3;         // B*M*3
    float* bb1_16 = xyz2s + BB * MM * 3;         // B*256*6
    float* bb1_64 = bb1_16 + BB * 256 * 6;       // B*64*6
    float* bb2_16 = bb1_64 + BB * 64 * 6;        // B*256*6
    float* bb2_64 = bb2_16 + BB * 256 * 6;       // B*64*6
    float4* rowBuf = (float4*)(bb2_64 + BB * 64 * 6); // B*N float4
    float4* colBuf = rowBuf + BB * NN;                // B*M float4
    float* sr2c   = (float*)(colBuf + BB * MM);  // B*M
    float* satrnc = sr2c  + BB * MM;             // B*M
    int*   rIdx   = (int*)(satrnc + BB * MM);    // B*N
    int*   cIdx   = rIdx  + BB * NN;             // B*M
    int*   rCnt   = cIdx  + BB * MM;             // B
    int*   cCnt   = rCnt  + BB;                  // B

    emd_sort<<<2 * BB, BLK, 0, stream>>>(xyz1, xyz2, xyz1s, xyz2s);
    emd_bbox_all<<<2 * (BB * 256 + BB * 64), 64, 0, stream>>>(
        xyz1s, xyz2s, bb1_16, bb1_64, bb2_16, bb2_64);
    emd_init<<<(BB * NN + 255) / 256, 256, 0, stream>>>(satl, satr, bsum,
                                                        slsum, scal, out);

    const double levels[10] = {-16384.0, -4096.0, -1024.0, -256.0, -64.0,
                               -16.0, -4.0, -1.0, -0.25, 0.0};
    const double LOG2E = 1.4426950408889634;
    float c[10], T[10];
    for (int l = 0; l < 10; ++l) {
        c[l] = (float)(levels[l] * LOG2E);
        T[l] = (l < 9) ? (float)(80.0 / (-levels[l] * LOG2E)) : 1e30f;
    }

    const int grid = BB * (NN / RPB);   // 512

    // level 0: box-pruned full-array path (dual-radius fused C(0)+A(1))
    emd_passA_p<<<grid, BLK, 0, stream>>>(xyz1s, xyz2s, satl, satr, sl,
                                          bb1_16, bb2_64, c[0], T[0]);
    emd_passB_p<<<grid, BLK, 0, stream>>>(xyz1s, xyz2s, sl, satr, sr2,
                                          bb2_16, bb1_64, c[0], T[0]);
    emd_passCA0_p<<<grid, BLK, 0, stream>>>(
        xyz1s, xyz2s, sl, satl, sr2, satr, out, bb1_16, bb2_64,
        c[0], c[1], T[1], T[0]);

    // levels 1..8: active-set compacted path
    compact_all<<<2 * BB, BLK, 0, stream>>>(xyz1s, xyz2s, satl, satr, sl,
                                            rowBuf, rIdx, rCnt,
                                            colBuf, cIdx, cCnt);
    for (int l = 1; l <= 8; ++l) {
        emd_passB_c<<<grid, BLK, 0, stream>>>(colBuf, cIdx, cCnt, rowBuf, rCnt,
                                              satr, sr2c, satrnc, bsum,
                                              (l == 8) ? 1 : 0, c[l]);
        if (l < 8) {
            emd_passCA0_c<<<grid, BLK, 0, stream>>>(
                rowBuf, rIdx, rCnt, colBuf, cCnt, sr2c, satrnc,
                satl, sl, out, c[l], c[l + 1]);
            compact_all<<<2 * BB, BLK, 0, stream>>>(xyz1s, xyz2s, satl, satr, sl,
                                                    rowBuf, rIdx, rCnt,
                                                    colBuf, cIdx, cCnt);
        } else {
            emd_passCA1_c<<<grid, BLK, 0, stream>>>(
                rowBuf, rIdx, rCnt, colBuf, cCnt, sr2c,
                satl, sl, bsum, slsum, out, c[8]);
        }
    }
    emd_lvl9_col<<<BB * MM / 256, 256, 0, stream>>>(xyz2s, satr, slsum, scal);
    emd_lvl9_cost<<<BB * NN / 256, 256, 0, stream>>>(xyz1s, sl, scal, out);
}

// Round 17
// 721.407 us; speedup vs baseline: 1.0617x; 1.0457x over previous
//
#include <hip/hip_runtime.h>

// EMD approx-match (Fan et al. approxmatch.cu), B=8, N=M=4096.
// R13 configuration (best measured, 722 us):
// Levels 0-2: sorted-cell single-tier box pruning with dual-radius fused CA0
// (groups beyond C-radius T[l] but inside A-radius T[l+1] run 6-op A-only body).
// Levels 3-8: exact-to-1e-8 active-set compaction, branch-free pipelined
// compact-to-compact sweeps. Level 9 closed form. Merged bookkeeping kernels.

#define BB 8
#define NN 4096
#define MM 4096
#define NPTS 4096

constexpr int   BLK   = 256;
constexpr int   S     = 16;
constexpr int   R     = 4;
constexpr int   RPB   = (BLK / S) * R;   // 64
constexpr int   CHUNK = 2048;
constexpr int   G     = (CHUNK / S) / 4; // 32 groups of 64 cols
constexpr float TAU   = 1e-8f;

#if defined(__has_builtin)
#if __has_builtin(__builtin_amdgcn_exp2f)
#define EXP2F(x) __builtin_amdgcn_exp2f(x)
#endif
#if __has_builtin(__builtin_amdgcn_logf)
#define LOG2F(x) __builtin_amdgcn_logf(x)
#endif
#endif
#ifndef EXP2F
#define EXP2F(x) exp2f(x)
#endif
#ifndef LOG2F
#define LOG2F(x) log2f(x)
#endif

// ---------- counting sort into 64 spatial cells (both clouds, one launch) ----------
__global__ void emd_sort(const float* __restrict__ x1, const float* __restrict__ x2,
                         float* __restrict__ s1, float* __restrict__ s2) {
    __shared__ int hist[64];
    __shared__ int cur[64];
    const int blk = blockIdx.x;
    const float* src = (blk < BB) ? x1 + (size_t)blk * NPTS * 3
                                  : x2 + (size_t)(blk - BB) * NPTS * 3;
    float* dst = (blk < BB) ? s1 + (size_t)blk * NPTS * 3
                            : s2 + (size_t)(blk - BB) * NPTS * 3;
    for (int i = threadIdx.x; i < 64; i += BLK) hist[i] = 0;
    __syncthreads();
    for (int i = threadIdx.x; i < NPTS; i += BLK) {
        float x = src[3*i], y = src[3*i+1], z = src[3*i+2];
        int cx = (int)(x * 4.0f); cx = cx < 0 ? 0 : (cx > 3 ? 3 : cx);
        int cy = (int)(y * 4.0f); cy = cy < 0 ? 0 : (cy > 3 ? 3 : cy);
        int cz = (int)(z * 4.0f); cz = cz < 0 ? 0 : (cz > 3 ? 3 : cz);
        atomicAdd(&hist[(cx << 4) | (cy << 2) | cz], 1);
    }
    __syncthreads();
    if (threadIdx.x == 0) {
        int acc = 0;
        for (int k = 0; k < 64; ++k) { cur[k] = acc; acc += hist[k]; }
    }
    __syncthreads();
    for (int i = threadIdx.x; i < NPTS; i += BLK) {
        float x = src[3*i], y = src[3*i+1], z = src[3*i+2];
        int cx = (int)(x * 4.0f); cx = cx < 0 ? 0 : (cx > 3 ? 3 : cx);
        int cy = (int)(y * 4.0f); cy = cy < 0 ? 0 : (cy > 3 ? 3 : cy);
        int cz = (int)(z * 4.0f); cz = cz < 0 ? 0 : (cz > 3 ? 3 : cz);
        int idx = atomicAdd(&cur[(cx << 4) | (cy << 2) | cz], 1);
        dst[3*idx] = x; dst[3*idx+1] = y; dst[3*idx+2] = z;
    }
}

// ---------- 16- and 64-point bboxes, one launch ----------
__global__ void emd_bbox_all(const float* __restrict__ x1s,
                             const float* __restrict__ x2s,
                             float* __restrict__ bb1_16, float* __restrict__ bb1_64,
                             float* __restrict__ bb2_16, float* __restrict__ bb2_64) {
    const int PER = BB * 256 + BB * 64;   // per cloud
    int id = blockIdx.x;
    int cloud = id / PER, r = id % PER;
    const float* xs = cloud ? x2s : x1s;
    float* bb; int gp, grp;
    if (r < BB * 256) { gp = 16; grp = r; bb = cloud ? bb2_16 : bb1_16; }
    else             { gp = 64; grp = r - BB * 256; bb = cloud ? bb2_64 : bb1_64; }
    const int lane = threadIdx.x;
    float xlo = 1e30f, xhi = -1e30f, ylo = 1e30f, yhi = -1e30f,
          zlo = 1e30f, zhi = -1e30f;
    if (lane < gp) {
        const float* p = xs + ((size_t)grp * gp + lane) * 3;
        xlo = xhi = p[0]; ylo = yhi = p[1]; zlo = zhi = p[2];
    }
    #pragma unroll
    for (int d = 1; d < 64; d <<= 1) {
        xlo = fminf(xlo, __shfl_xor(xlo, d)); xhi = fmaxf(xhi, __shfl_xor(xhi, d));
        ylo = fminf(ylo, __shfl_xor(ylo, d)); yhi = fmaxf(yhi, __shfl_xor(yhi, d));
        zlo = fminf(zlo, __shfl_xor(zlo, d)); zhi = fmaxf(zhi, __shfl_xor(zhi, d));
    }
    if (lane == 0) {
        float* o = bb + (size_t)grp * 6;
        o[0]=xlo; o[1]=xhi; o[2]=ylo; o[3]=yhi; o[4]=zlo; o[5]=zhi;
    }
}

__global__ void emd_init(float* __restrict__ satl, float* __restrict__ satr,
                         float* __restrict__ bsum, float* __restrict__ slsum,
                         float* __restrict__ scal, float* __restrict__ out) {
    int i = blockIdx.x * blockDim.x + threadIdx.x;
    if (i < BB * NN) satl[i] = 1.0f;
    if (i < BB * MM) satr[i] = 1.0f;
    if (i < BB)      bsum[i] = 0.0f;
    if (i < BB)      slsum[i] = 0.0f;
    if (i < BB * 5)  scal[i] = 0.0f;
    if (i == 0)      out[0]  = 0.0f;
}

// ---------- merged active-set compaction: blocks 0..B-1 cols, B..2B-1 rows ----------
__global__ void compact_all(const float* __restrict__ xyz1s,
                            const float* __restrict__ xyz2s,
                            const float* __restrict__ satl,
                            const float* __restrict__ satr,
                            float* __restrict__ sl,
                            float4* __restrict__ rowBuf, int* __restrict__ rIdx,
                            int* __restrict__ rCnt,
                            float4* __restrict__ colBuf, int* __restrict__ cIdx,
                            int* __restrict__ cCnt) {
    __shared__ int cnts[BLK];
    const bool isRow = blockIdx.x >= BB;
    const int b = isRow ? (blockIdx.x - BB) : blockIdx.x;
    const int PER = NPTS / BLK;   // 16
    const float* sb = (isRow ? satl : satr) + (size_t)b * NPTS;
    const float* xb = (isRow ? xyz1s : xyz2s) + (size_t)b * NPTS * 3;
    float* slb = sl + (size_t)b * NN;
    const int st = threadIdx.x * PER;
    int c = 0;
    for (int i = 0; i < PER; ++i) c += (sb[st + i] > TAU) ? 1 : 0;
    cnts[threadIdx.x] = c;
    __syncthreads();
    for (int d = 1; d < BLK; d <<= 1) {
        int v = cnts[threadIdx.x];
        int u = (threadIdx.x >= d) ? cnts[threadIdx.x - d] : 0;
        __syncthreads();
        cnts[threadIdx.x] = v + u;
        __syncthreads();
    }
    const int total = cnts[BLK - 1];
    int off = cnts[threadIdx.x] - c;
    if (isRow) {
        for (int i = 0; i < PER; ++i) {
            int n = st + i;
            if (sb[n] > TAU) {
                rowBuf[(size_t)b * NN + off] =
                    make_float4(xb[3*n], xb[3*n+1], xb[3*n+2], slb[n]);
                rIdx[(size_t)b * NN + off] = n;
                ++off;
            } else if (slb[n] != 0.0f) {
                slb[n] = 0.0f;   // kill stale sl for level-9 closed form
            }
        }
        for (int i = total + threadIdx.x; i < NN; i += BLK) {
            rowBuf[(size_t)b * NN + i] = make_float4(0.f, 0.f, 0.f, 0.f);
            rIdx[(size_t)b * NN + i] = 0;
        }
        if (threadIdx.x == 0) rCnt[b] = total;
    } else {
        for (int i = 0; i < PER; ++i) {
            int m = st + i;
            if (sb[m] > TAU) {
                colBuf[(size_t)b * MM + off] =
                    make_float4(xb[3*m], xb[3*m+1], xb[3*m+2], sb[m]);
                cIdx[(size_t)b * MM + off] = m;
                ++off;
            }
        }
        for (int i = total + threadIdx.x; i < MM; i += BLK) {
            colBuf[(size_t)b * MM + i] = make_float4(0.f, 0.f, 0.f, 0.f);
            cIdx[(size_t)b * MM + i] = 0;
        }
        if (threadIdx.x == 0) cCnt[b] = total;
    }
}

// ---------- shared macros ----------
#define AB_LOAD(vv, gg)                                          \
    _Pragma("unroll")                                            \
    for (int k = 0; k < 4; ++k) vv[k] = q[((gg)*4 + k)*S + s];

#define AB_COMP(vv)                                              \
    _Pragma("unroll")                                            \
    for (int k = 0; k < 4; ++k) {                                \
        float4 v = vv[k];                                        \
        _Pragma("unroll")                                        \
        for (int r = 0; r < R; ++r) {                            \
            float a0 = v.w + cpp[r];                             \
            float a1 = fmaf(zs[r], v.z, a0);                     \
            float a2 = fmaf(ys[r], v.y, a1);                     \
            float arg = fmaf(xs[r], v.x, a2);                    \
            acc[r] += EXP2F(arg);                                \
        }                                                        \
    }

#define RED_S(v)                                                 \
    v += __shfl_xor(v, 1);  v += __shfl_xor(v, 2);               \
    v += __shfl_xor(v, 4);  v += __shfl_xor(v, 8);

#define RED_W(v)                                                 \
    v += __shfl_xor(v, 1);  v += __shfl_xor(v, 2);               \
    v += __shfl_xor(v, 4);  v += __shfl_xor(v, 8);               \
    v += __shfl_xor(v, 16); v += __shfl_xor(v, 32);

#define BOX_SETUP(rbb)                                           \
    const float* rb = (rbb) + (size_t)(b * 256 + tile * 4 + (threadIdx.x >> 6)) * 6; \
    const float rx0 = rb[0], rx1 = rb[1], ry0 = rb[2], ry1 = rb[3], \
                rz0 = rb[4], rz1 = rb[5];

#define BOX_D2M(cbb, c0, gs, d2m)                                \
    const float* cb = (cbb) + (size_t)(b * 64 + ((c0) >> 6) + (gs)) * 6; \
    float gx = fmaxf(0.0f, fmaxf(cb[0] - rx1, rx0 - cb[1]));     \
    float gy = fmaxf(0.0f, fmaxf(cb[2] - ry1, ry0 - cb[3]));     \
    float gz = fmaxf(0.0f, fmaxf(cb[4] - rz1, rz0 - cb[5]));     \
    float d2m = fmaf(gx, gx, fmaf(gy, gy, gz * gz));

// ---------- Pass A (level 0, pruned) ----------
__global__ __launch_bounds__(BLK, 2) void emd_passA_p(
        const float* __restrict__ xyz1, const float* __restrict__ xyz2,
        const float* __restrict__ satl, const float* __restrict__ satr,
        float* __restrict__ sl, const float* __restrict__ rbb,
        const float* __restrict__ cbb, float c, float T) {
    __shared__ float4 q[CHUNK];
    const int b    = blockIdx.x / (NN / RPB);
    const int tile = blockIdx.x % (NN / RPB);
    const float* x2b = xyz2 + (size_t)b * MM * 3;
    const float* srb = satr + (size_t)b * MM;

    const int g = threadIdx.x / S, s = threadIdx.x % S;
    const int n0 = tile * RPB + g * R;
    const float* p = xyz1 + ((size_t)b * NN + n0) * 3;
    const float m2c = -2.0f * c;
    float xs[R], ys[R], zs[R], cpp[R], acc[R];
    #pragma unroll
    for (int r = 0; r < R; ++r) {
        float x = p[3*r], y = p[3*r+1], z = p[3*r+2];
        cpp[r] = c * (x*x + y*y + z*z);
        xs[r] = m2c * x; ys[r] = m2c * y; zs[r] = m2c * z;
        acc[r] = 0.0f;
    }
    BOX_SETUP(rbb);

    for (int c0 = 0; c0 < MM; c0 += CHUNK) {
        __syncthreads();
        for (int m = threadIdx.x; m < CHUNK; m += BLK) {
            int mm = c0 + m;
            float xx = x2b[3*mm], yy = x2b[3*mm+1], zz = x2b[3*mm+2];
            float qq = xx*xx + yy*yy + zz*zz;
            q[m] = make_float4(xx, yy, zz, fmaf(c, qq, LOG2F(srb[mm])));
        }
        __syncthreads();
        for (int gs = 0; gs < G; ++gs) {
            BOX_D2M(cbb, c0, gs, d2m);
            if (d2m > T) continue;
            float4 va[4];
            AB_LOAD(va, gs);
            AB_COMP(va);
        }
    }
    #pragma unroll
    for (int r = 0; r < R; ++r) { RED_S(acc[r]); }
    if (s == 0) {
        #pragma unroll
        for (int r = 0; r < R; ++r) {
            int gi = b * NN + n0 + r;
            sl[gi] = satl[gi] / (acc[r] + 1e-9f);
        }
    }
}

// ---------- Pass B (levels 0..2, pruned, full arrays) ----------
__global__ __launch_bounds__(BLK, 2) void emd_passB_p(
        const float* __restrict__ xyz1, const float* __restrict__ xyz2,
        const float* __restrict__ sl, float* __restrict__ satr,
        float* __restrict__ sr2, const float* __restrict__ rbb,
        const float* __restrict__ cbb, float c, float T) {
    __shared__ float4 q[CHUNK];
    const int b    = blockIdx.x / (MM / RPB);
    const int tile = blockIdx.x % (MM / RPB);
    const float* x1b = xyz1 + (size_t)b * NN * 3;
    const float* slb = sl + (size_t)b * NN;

    const int g = threadIdx.x / S, s = threadIdx.x % S;
    const int m0 = tile * RPB + g * R;
    const float* qp = xyz2 + ((size_t)b * MM + m0) * 3;
    const float m2c = -2.0f * c;
    float xs[R], ys[R], zs[R], cpp[R], acc[R];
    #pragma unroll
    for (int r = 0; r < R; ++r) {
        float x = qp[3*r], y = qp[3*r+1], z = qp[3*r+2];
        cpp[r] = c * (x*x + y*y + z*z);
        xs[r] = m2c * x; ys[r] = m2c * y; zs[r] = m2c * z;
        acc[r] = 0.0f;
    }
    BOX_SETUP(rbb);

    for (int c0 = 0; c0 < NN; c0 += CHUNK) {
        __syncthreads();
        for (int n = threadIdx.x; n < CHUNK; n += BLK) {
            int nn = c0 + n;
            float xx = x1b[3*nn], yy = x1b[3*nn+1], zz = x1b[3*nn+2];
            float pp = xx*xx + yy*yy + zz*zz;
            q[n] = make_float4(xx, yy, zz, fmaf(c, pp, LOG2F(slb[nn])));
        }
        __syncthreads();
        for (int gs = 0; gs < G; ++gs) {
            BOX_D2M(cbb, c0, gs, d2m);
            if (d2m > T) continue;
            float4 va[4];
            AB_LOAD(va, gs);
            AB_COMP(va);
        }
    }
    #pragma unroll
    for (int r = 0; r < R; ++r) { RED_S(acc[r]); }
    if (s == 0) {
        #pragma unroll
        for (int r = 0; r < R; ++r) {
            int gi = b * MM + m0 + r;
            float sr    = satr[gi];
            float ss2   = acc[r] * sr;
            float ratio = fminf(sr / (ss2 + 1e-9f), 1.0f);
            float sn    = fmaxf(sr - ss2 * ratio, 0.0f);
            sr2[gi]  = sr * ratio;
            satr[gi] = sn;
        }
    }
}

// ---------- Fused C(l)+A(l+1), dual-radius pruned (levels 0..2) ----------
#define CA0_LOAD(vv, ww, gg)                                     \
    _Pragma("unroll")                                            \
    for (int k = 0; k < 4; ++k) {                                \
        int idx = ((gg)*4 + k)*S + s;                            \
        vv[k] = q[idx]; ww[k] = w[idx];                          \
    }

#define CA0_COMP(vv, ww)                                         \
    _Pragma("unroll")                                            \
    for (int k = 0; k < 4; ++k) {                                \
        float4 v = vv[k]; float2 wv = ww[k];                     \
        _Pragma("unroll")                                        \
        for (int r = 0; r < R; ++r) {                            \
            float a0 = v.w + cnpp[r];                            \
            float a1 = fmaf(zs[r], v.z, a0);                     \
            float a2 = fmaf(ys[r], v.y, a1);                     \
            float arg = fmaf(xs[r], v.x, a2);                    \
            float en  = EXP2F(arg);                              \
            acc2[r] = fmaf(en, wv.y, acc2[r]);                   \
            float e2 = en * en;                                  \
            float t  = (e2 * e2) * wv.x;                         \
            rd[r]   += t;                                        \
            costA[r] = fmaf(t, arg, costA[r]);                   \
        }                                                        \
    }

// A-only body: C terms < 2^-80 in this annulus (d2m > TC)
#define CA0_COMP_AONLY(vv, ww)                                   \
    _Pragma("unroll")                                            \
    for (int k = 0; k < 4; ++k) {                                \
        float4 v = vv[k]; float2 wv = ww[k];                     \
        _Pragma("unroll")                                        \
        for (int r = 0; r < R; ++r) {                            \
            float a0 = v.w + cnpp[r];                            \
            float a1 = fmaf(zs[r], v.z, a0);                     \
            float a2 = fmaf(ys[r], v.y, a1);                     \
            float arg = fmaf(xs[r], v.x, a2);                    \
            float en  = EXP2F(arg);                              \
            acc2[r] = fmaf(en, wv.y, acc2[r]);                   \
        }                                                        \
    }

__global__ __launch_bounds__(BLK, 2) void emd_passCA0_p(
        const float* __restrict__ xyz1, const float* __restrict__ xyz2,
        float* __restrict__ sl, float* __restrict__ satl,
        const float* __restrict__ sr2, const float* __restrict__ satr_next,
        float* __restrict__ out, const float* __restrict__ rbb,
        const float* __restrict__ cbb, float cl, float cn,
        float T, float TC) {
    __shared__ float4 q[CHUNK];
    __shared__ float2 w[CHUNK];
    const int b    = blockIdx.x / (NN / RPB);
    const int tile = blockIdx.x % (NN / RPB);
    const float* x2b = xyz2 + (size_t)b * MM * 3;
    const float* s2b = sr2 + (size_t)b * MM;
    const float* srb = satr_next + (size_t)b * MM;

    const int g = threadIdx.x / S, s = threadIdx.x % S;
    const int n0 = tile * RPB + g * R;
    const float* pp_ = xyz1 + ((size_t)b * NN + n0) * 3;
    const float m2cn = -2.0f * cn;
    const float icn  = 1.0f / cn;
    float xs[R], ys[R], zs[R], cnpp[R], rd[R], costA[R], acc2[R], slv[R];
    #pragma unroll
    for (int r = 0; r < R; ++r) {
        float x = pp_[3*r], y = pp_[3*r+1], z = pp_[3*r+2];
        cnpp[r] = cn * (x*x + y*y + z*z);
        xs[r] = m2cn * x; ys[r] = m2cn * y; zs[r] = m2cn * z;
        rd[r] = 0.0f; costA[r] = 0.0f; acc2[r] = 0.0f;
        slv[r] = sl[b * NN + n0 + r];
    }
    BOX_SETUP(rbb);

    for (int c0 = 0; c0 < MM; c0 += CHUNK) {
        __syncthreads();
        for (int m = threadIdx.x; m < CHUNK; m += BLK) {
            int mm = c0 + m;
            float xx = x2b[3*mm], yy = x2b[3*mm+1], zz = x2b[3*mm+2];
            float qq = xx*xx + yy*yy + zz*zz;
            q[m] = make_float4(xx, yy, zz, cn * qq);
            w[m] = make_float2(s2b[mm], srb[mm]);
        }
        __syncthreads();
        for (int gs = 0; gs < G; ++gs) {
            BOX_D2M(cbb, c0, gs, d2m);
            if (d2m > T) continue;
            float4 va[4]; float2 wa[4];
            CA0_LOAD(va, wa, gs);
            if (d2m > TC) {
                CA0_COMP_AONLY(va, wa);
            } else {
                CA0_COMP(va, wa);
            }
        }
    }

    #pragma unroll
    for (int r = 0; r < R; ++r) { RED_S(rd[r]); RED_S(acc2[r]); }

    float csum = 0.0f;
    #pragma unroll
    for (int r = 0; r < R; ++r) csum += (costA[r] * icn) * slv[r];
    RED_W(csum);
    if ((threadIdx.x & 63) == 0)
        atomicAdd(out, csum * (1.0f / (float)(BB * NN)));

    if (s == 0) {
        #pragma unroll
        for (int r = 0; r < R; ++r) {
            int gi = b * NN + n0 + r;
            float sa = fmaxf(satl[gi] - rd[r] * slv[r], 0.0f);
            satl[gi] = sa;
            sl[gi] = sa / (acc2[r] + 1e-9f);
        }
    }
}

// ---------- Compact Pass B (levels 3..8) ----------
__global__ __launch_bounds__(BLK, 2) void emd_passB_c(
        const float4* __restrict__ colBuf, const int* __restrict__ cIdx,
        const int* __restrict__ cCnt, const float4* __restrict__ rowBuf,
        const int* __restrict__ rCnt, float* __restrict__ satr,
        float* __restrict__ sr2c, float* __restrict__ satrnc,
        float* __restrict__ bsum, int do_sum, float c) {
    __shared__ float4 q[CHUNK];
    const int b    = blockIdx.x / (MM / RPB);
    const int tile = blockIdx.x % (MM / RPB);
    const int Mc = cCnt[b], Nc = rCnt[b];
    if (tile * RPB >= Mc) return;
    const float4* rb = rowBuf + (size_t)b * NN;

    const int g = threadIdx.x / S, s = threadIdx.x % S;
    const int m0 = tile * RPB + g * R;
    const float m2c = -2.0f * c;
    float xs[R], ys[R], zs[R], cpp[R], acc[R], srv[R];
    #pragma unroll
    for (int r = 0; r < R; ++r) {
        float4 cv = colBuf[(size_t)b * MM + m0 + r];
        srv[r] = cv.w;
        cpp[r] = c * (cv.x*cv.x + cv.y*cv.y + cv.z*cv.z);
        xs[r] = m2c * cv.x; ys[r] = m2c * cv.y; zs[r] = m2c * cv.z;
        acc[r] = 0.0f;
    }

    const int nch = (Nc + CHUNK - 1) / CHUNK;
    for (int ci = 0; ci < nch; ++ci) {
        const int c0 = ci * CHUNK;
        __syncthreads();
        for (int n = threadIdx.x; n < CHUNK; n += BLK) {
            int nn = c0 + n;
            if (nn < Nc) {
                float4 rv = rb[nn];
                float pp = rv.x*rv.x + rv.y*rv.y + rv.z*rv.z;
                q[n] = make_float4(rv.x, rv.y, rv.z, fmaf(c, pp, LOG2F(rv.w)));
            } else {
                q[n] = make_float4(0.f, 0.f, 0.f, -1e30f);
            }
        }
        __syncthreads();
        int rem = Nc - c0; if (rem > CHUNK) rem = CHUNK;
        const int Gact = (rem + S*4 - 1) / (S*4);
        float4 va[4], vb[4];
        AB_LOAD(va, 0);
        #pragma unroll 1
        for (int gs = 0; gs < Gact; gs += 2) {
            if (gs + 1 < Gact) { AB_LOAD(vb, gs + 1); }
            AB_COMP(va);
            if (gs + 2 < Gact) { AB_LOAD(va, gs + 2); }
            if (gs + 1 < Gact) { AB_COMP(vb); }
        }
    }
    #pragma unroll
    for (int r = 0; r < R; ++r) { RED_S(acc[r]); }
    float part = 0.0f;
    if (s == 0) {
        #pragma unroll
        for (int r = 0; r < R; ++r) {
            if (m0 + r < Mc) {
                float sr    = srv[r];
                float ss2   = acc[r] * sr;
                float ratio = fminf(sr / (ss2 + 1e-9f), 1.0f);
                float sn    = fmaxf(sr - ss2 * ratio, 0.0f);
                size_t ci2 = (size_t)b * MM + m0 + r;
                sr2c[ci2]   = sr * ratio;
                satrnc[ci2] = sn;
                satr[(size_t)b * MM + cIdx[ci2]] = sn;
                part += sn;
            }
        }
    }
    if (do_sum) {
        RED_W(part);
        if ((threadIdx.x & 63) == 0) atomicAdd(&bsum[b], part);
    }
}

// ---------- Compact fused C(l)+A(l+1) (levels 3..7) ----------
__global__ __launch_bounds__(BLK, 2) void emd_passCA0_c(
        const float4* __restrict__ rowBuf, const int* __restrict__ rIdx,
        const int* __restrict__ rCnt, const float4* __restrict__ colBuf,
        const int* __restrict__ cCnt, const float* __restrict__ sr2c,
        const float* __restrict__ satrnc, float* __restrict__ satl,
        float* __restrict__ sl, float* __restrict__ out, float cl, float cn) {
    __shared__ float4 q[CHUNK];
    __shared__ float2 w[CHUNK];
    const int b    = blockIdx.x / (NN / RPB);
    const int tile = blockIdx.x % (NN / RPB);
    const int Nc = rCnt[b], Mc = cCnt[b];
    if (tile * RPB >= Nc) return;
    const float4* cbp = colBuf + (size_t)b * MM;
    const float* s2p = sr2c + (size_t)b * MM;
    const float* snp = satrnc + (size_t)b * MM;

    const int g = threadIdx.x / S, s = threadIdx.x % S;
    const int n0 = tile * RPB + g * R;
    const float m2cn = -2.0f * cn;
    const float icn  = 1.0f / cn;
    float xs[R], ys[R], zs[R], cnpp[R], rd[R], costA[R], acc2[R], slv[R];
    #pragma unroll
    for (int r = 0; r < R; ++r) {
        float4 rv = rowBuf[(size_t)b * NN + n0 + r];
        slv[r] = rv.w;
        cnpp[r] = cn * (rv.x*rv.x + rv.y*rv.y + rv.z*rv.z);
        xs[r] = m2cn * rv.x; ys[r] = m2cn * rv.y; zs[r] = m2cn * rv.z;
        rd[r] = 0.0f; costA[r] = 0.0f; acc2[r] = 0.0f;
    }

    const int nch = (Mc + CHUNK - 1) / CHUNK;
    for (int ci = 0; ci < nch; ++ci) {
        const int c0 = ci * CHUNK;
        __syncthreads();
        for (int m = threadIdx.x; m < CHUNK; m += BLK) {
            int mm = c0 + m;
            if (mm < Mc) {
                float4 cv = cbp[mm];
                float qq = cv.x*cv.x + cv.y*cv.y + cv.z*cv.z;
                q[m] = make_float4(cv.x, cv.y, cv.z, cn * qq);
                w[m] = make_float2(s2p[mm], snp[mm]);
            } else {
                q[m] = make_float4(0.f, 0.f, 0.f, 0.f);
                w[m] = make_float2(0.f, 0.f);
            }
        }
        __syncthreads();
        int rem = Mc - c0; if (rem > CHUNK) rem = CHUNK;
        const int Gact = (rem + S*4 - 1) / (S*4);
        float4 va[4], vb[4]; float2 wa[4], wb[4];
        CA0_LOAD(va, wa, 0);
        #pragma unroll 1
        for (int gs = 0; gs < Gact; gs += 2) {
            if (gs + 1 < Gact) { CA0_LOAD(vb, wb, gs + 1); }
            CA0_COMP(va, wa);
            if (gs + 2 < Gact) { CA0_LOAD(va, wa, gs + 2); }
            if (gs + 1 < Gact) { CA0_COMP(vb, wb); }
        }
    }

    #pragma unroll
    for (int r = 0; r < R; ++r) { RED_S(rd[r]); RED_S(acc2[r]); }

    float csum = 0.0f;
    #pragma unroll
    for (int r = 0; r < R; ++r) csum += (costA[r] * icn) * slv[r];
    RED_W(csum);
    if ((threadIdx.x & 63) == 0)
        atomicAdd(out, csum * (1.0f / (float)(BB * NN)));

    if (s == 0) {
        #pragma unroll
        for (int r = 0; r < R; ++r) {
            if (n0 + r < Nc) {
                int gi = b * NN + rIdx[(size_t)b * NN + n0 + r];
                float sa = fmaxf(satl[gi] - rd[r] * slv[r], 0.0f);
                satl[gi] = sa;
                sl[gi] = sa / (acc2[r] + 1e-9f);
            }
        }
    }
}

// ---------- Compact fused C(8)+A(9) ----------
#define CA1_LOAD(vv, aa, gg)                                     \
    _Pragma("unroll")                                            \
    for (int k = 0; k < 4; ++k) {                                \
        int idx = ((gg)*4 + k)*S + s;                            \
        vv[k] = q[idx]; aa[k] = qa[idx];                         \
    }

#define CA1_COMP(vv, aa)                                         \
    _Pragma("unroll")                                            \
    for (int k = 0; k < 4; ++k) {                                \
        float4 v = vv[k]; float lw = aa[k];                      \
        _Pragma("unroll")                                        \
        for (int r = 0; r < R; ++r) {                            \
            float a0 = v.w + clpp[r];                            \
            float a1 = fmaf(zs[r], v.z, a0);                     \
            float a2 = fmaf(ys[r], v.y, a1);                     \
            float arg = fmaf(xs[r], v.x, a2);                    \
            float t   = EXP2F(arg);                              \
            rd[r] += t;                                          \
            c1[r] = fmaf(t, arg, c1[r]);                         \
            c2[r] = fmaf(t, lw, c2[r]);                          \
        }                                                        \
    }

__global__ __launch_bounds__(BLK, 2) void emd_passCA1_c(
        const float4* __restrict__ rowBuf, const int* __restrict__ rIdx,
        const int* __restrict__ rCnt, const float4* __restrict__ colBuf,
        const int* __restrict__ cCnt, const float* __restrict__ sr2c,
        float* __restrict__ satl, float* __restrict__ sl,
        const float* __restrict__ bsum, float* __restrict__ slsum,
        float* __restrict__ out, float cl) {
    __shared__ float4 q[CHUNK];
    __shared__ float  qa[CHUNK];
    const int b    = blockIdx.x / (NN / RPB);
    const int tile = blockIdx.x % (NN / RPB);
    const int Nc = rCnt[b], Mc = cCnt[b];
    if (tile * RPB >= Nc) return;
    const float4* cbp = colBuf + (size_t)b * MM;
    const float* s2p = sr2c + (size_t)b * MM;

    const int g = threadIdx.x / S, s = threadIdx.x % S;
    const int n0 = tile * RPB + g * R;
    const float m2cl = -2.0f * cl;
    const float icl  = 1.0f / cl;
    float xs[R], ys[R], zs[R], clpp[R], rd[R], c1[R], c2[R], slv[R];
    #pragma unroll
    for (int r = 0; r < R; ++r) {
        float4 rv = rowBuf[(size_t)b * NN + n0 + r];
        slv[r] = rv.w;
        clpp[r] = cl * (rv.x*rv.x + rv.y*rv.y + rv.z*rv.z);
        xs[r] = m2cl * rv.x; ys[r] = m2cl * rv.y; zs[r] = m2cl * rv.z;
        rd[r] = 0.0f; c1[r] = 0.0f; c2[r] = 0.0f;
    }

    const int nch = (Mc + CHUNK - 1) / CHUNK;
    for (int ci = 0; ci < nch; ++ci) {
        const int c0 = ci * CHUNK;
        __syncthreads();
        for (int m = threadIdx.x; m < CHUNK; m += BLK) {
            int mm = c0 + m;
            if (mm < Mc) {
                float4 cv = cbp[mm];
                float qq = cv.x*cv.x + cv.y*cv.y + cv.z*cv.z;
                float lw = LOG2F(fmaxf(s2p[mm], 1e-30f));
                q[m]  = make_float4(cv.x, cv.y, cv.z, fmaf(cl, qq, lw));
                qa[m] = lw;
            } else {
                q[m]  = make_float4(0.f, 0.f, 0.f, -1e30f);
                qa[m] = 0.f;
            }
        }
        __syncthreads();
        int rem = Mc - c0; if (rem > CHUNK) rem = CHUNK;
        const int Gact = (rem + S*4 - 1) / (S*4);
        float4 va[4], vb[4]; float aa[4], ab[4];
        CA1_LOAD(va, aa, 0);
        #pragma unroll 1
        for (int gs = 0; gs < Gact; gs += 2) {
            if (gs + 1 < Gact) { CA1_LOAD(vb, ab, gs + 1); }
            CA1_COMP(va, aa);
            if (gs + 2 < Gact) { CA1_LOAD(va, aa, gs + 2); }
            if (gs + 1 < Gact) { CA1_COMP(vb, ab); }
        }
    }

    #pragma unroll
    for (int r = 0; r < R; ++r) { RED_S(rd[r]); }

    float csum = 0.0f;
    #pragma unroll
    for (int r = 0; r < R; ++r) csum += ((c1[r] - c2[r]) * icl) * slv[r];
    RED_W(csum);
    if ((threadIdx.x & 63) == 0)
        atomicAdd(out, csum * (1.0f / (float)(BB * NN)));

    float part = 0.0f;
    if (s == 0) {
        float bs = bsum[b];
        #pragma unroll
        for (int r = 0; r < R; ++r) {
            if (n0 + r < Nc) {
                int gi = b * NN + rIdx[(size_t)b * NN + n0 + r];
                float sa = fmaxf(satl[gi] - rd[r] * slv[r], 0.0f);
                satl[gi] = sa;
                float s9 = sa / (bs + 1e-9f);
                sl[gi] = s9;
                part += s9;
            }
        }
    }
    RED_W(part);
    if ((threadIdx.x & 63) == 0) atomicAdd(&slsum[b], part);
}

// ---------- Level 9 (coef 0) closed form ----------
__global__ void emd_lvl9_col(const float* __restrict__ xyz2,
                             const float* __restrict__ satr,
                             const float* __restrict__ slsum,
                             float* __restrict__ scal) {
    int i = blockIdx.x * blockDim.x + threadIdx.x;
    int b = i / MM;
    const float* qp = xyz2 + (size_t)i * 3;
    float sr = satr[i];
    float ss2 = sr * slsum[b];
    float ratio = fminf(sr / (ss2 + 1e-9f), 1.0f);
    float s2 = sr * ratio;
    float x = qp[0], y = qp[1], z = qp[2];
    float v0 = s2, v1 = s2*x, v2 = s2*y, v3 = s2*z;
    float v4 = s2 * (x*x + y*y + z*z);
    #pragma unroll
    for (int d = 1; d < 64; d <<= 1) {
        v0 += __shfl_xor(v0, d); v1 += __shfl_xor(v1, d);
        v2 += __shfl_xor(v2, d); v3 += __shfl_xor(v3, d);
        v4 += __shfl_xor(v4, d);
    }
    if ((threadIdx.x & 63) == 0) {
        atomicAdd(&scal[b*5+0], v0); atomicAdd(&scal[b*5+1], v1);
        atomicAdd(&scal[b*5+2], v2); atomicAdd(&scal[b*5+3], v3);
        atomicAdd(&scal[b*5+4], v4);
    }
}

__global__ void emd_lvl9_cost(const float* __restrict__ xyz1,
                              const float* __restrict__ sl,
                              const float* __restrict__ scal,
                              float* __restrict__ out) {
    int i = blockIdx.x * blockDim.x + threadIdx.x;
    int b = i / NN;
    float W  = scal[b*5+0], Wx = scal[b*5+1], Wy = scal[b*5+2];
    float Wz = scal[b*5+3], Q  = scal[b*5+4];
    const float* p = xyz1 + (size_t)i * 3;
    float x = p[0], y = p[1], z = p[2];
    float pp = x*x + y*y + z*z;
    float dotw = x*Wx + y*Wy + z*Wz;
    float c = sl[i] * (pp * W + Q - 2.0f * dotw);
    #pragma unroll
    for (int d = 1; d < 64; d <<= 1) c += __shfl_xor(c, d);
    if ((threadIdx.x & 63) == 0)
        atomicAdd(out, c * (1.0f / (float)(BB * NN)));
}

extern "C" void kernel_launch(void* const* d_in, const int* in_sizes, int n_in,
                              void* d_out, int out_size, void* d_ws, size_t ws_size,
                              hipStream_t stream) {
    const float* xyz1 = (const float*)d_in[0];
    const float* xyz2 = (const float*)d_in[1];
    float* out  = (float*)d_out;

    float* satl   = (float*)d_ws;                // B*N
    float* sl     = satl  + BB * NN;             // B*N
    float* satr   = sl    + BB * NN;             // B*M
    float* sr2    = satr  + BB * MM;             // B*M (pruned levels)
    float* bsum   = sr2   + BB * MM;             // B
    float* slsum  = bsum  + BB;                  // B
    float* scal   = slsum + BB;                  // B*5
    float* xyz1s  = scal  + BB * 5;              // B*N*3
    float* xyz2s  = xyz1s + BB * NN * 3;         // B*M*3
    float* bb1_16 = xyz2s + BB * MM * 3;         // B*256*6
    float* bb1_64 = bb1_16 + BB * 256 * 6;       // B*64*6
    float* bb2_16 = bb1_64 + BB * 64 * 6;        // B*256*6
    float* bb2_64 = bb2_16 + BB * 256 * 6;       // B*64*6
    float4* rowBuf = (float4*)(bb2_64 + BB * 64 * 6); // B*N float4
    float4* colBuf = rowBuf + BB * NN;                // B*M float4
    float* sr2c   = (float*)(colBuf + BB * MM);  // B*M
    float* satrnc = sr2c  + BB * MM;             // B*M
    int*   rIdx   = (int*)(satrnc + BB * MM);    // B*N
    int*   cIdx   = rIdx  + BB * NN;             // B*M
    int*   rCnt   = cIdx  + BB * MM;             // B
    int*   cCnt   = rCnt  + BB;                  // B

    emd_sort<<<2 * BB, BLK, 0, stream>>>(xyz1, xyz2, xyz1s, xyz2s);
    emd_bbox_all<<<2 * (BB * 256 + BB * 64), 64, 0, stream>>>(
        xyz1s, xyz2s, bb1_16, bb1_64, bb2_16, bb2_64);
    emd_init<<<(BB * NN + 255) / 256, 256, 0, stream>>>(satl, satr, bsum,
                                                        slsum, scal, out);

    const double levels[10] = {-16384.0, -4096.0, -1024.0, -256.0, -64.0,
                               -16.0, -4.0, -1.0, -0.25, 0.0};
    const double LOG2E = 1.4426950408889634;
    float c[10], T[10];
    for (int l = 0; l < 10; ++l) {
        c[l] = (float)(levels[l] * LOG2E);
        T[l] = (l < 9) ? (float)(80.0 / (-levels[l] * LOG2E)) : 1e30f;
    }

    const int grid = BB * (NN / RPB);   // 512

    // levels 0..2: box-pruned full-array path (dual-radius fused CA0)
    emd_passA_p<<<grid, BLK, 0, stream>>>(xyz1s, xyz2s, satl, satr, sl,
                                          bb1_16, bb2_64, c[0], T[0]);
    for (int l = 0; l <= 2; ++l) {
        emd_passB_p<<<grid, BLK, 0, stream>>>(xyz1s, xyz2s, sl, satr, sr2,
                                              bb2_16, bb1_64, c[l], T[l]);
        emd_passCA0_p<<<grid, BLK, 0, stream>>>(
            xyz1s, xyz2s, sl, satl, sr2, satr, out, bb1_16, bb2_64,
            c[l], c[l + 1], T[l + 1], T[l]);
    }

    // levels 3..8: active-set compacted path
    compact_all<<<2 * BB, BLK, 0, stream>>>(xyz1s, xyz2s, satl, satr, sl,
                                            rowBuf, rIdx, rCnt,
                                            colBuf, cIdx, cCnt);
    for (int l = 3; l <= 8; ++l) {
        emd_passB_c<<<grid, BLK, 0, stream>>>(colBuf, cIdx, cCnt, rowBuf, rCnt,
                                              satr, sr2c, satrnc, bsum,
                                              (l == 8) ? 1 : 0, c[l]);
        if (l < 8) {
            emd_passCA0_c<<<grid, BLK, 0, stream>>>(
                rowBuf, rIdx, rCnt, colBuf, cCnt, sr2c, satrnc,
                satl, sl, out, c[l], c[l + 1]);
            compact_all<<<2 * BB, BLK, 0, stream>>>(xyz1s, xyz2s, satl, satr, sl,
                                                    rowBuf, rIdx, rCnt,
                                                    colBuf, cIdx, cCnt);
        } else {
            emd_passCA1_c<<<grid, BLK, 0, stream>>>(
                rowBuf, rIdx, rCnt, colBuf, cCnt, sr2c,
                satl, sl, bsum, slsum, out, c[8]);
        }
    }
    emd_lvl9_col<<<BB * MM / 256, 256, 0, stream>>>(xyz2s, satr, slsum, scal);
    emd_lvl9_cost<<<BB * NN / 256, 256, 0, stream>>>(xyz1s, sl, scal, out);
}